// Round 10
// baseline (20131.888 us; speedup 1.0000x reference)
//
#include <hip/hip_runtime.h>
#include <hip/hip_fp16.h>

#define N 4096
#define L 4096
#define NPART 16   // i-chunks (rows 256 each)
#define NJB 32     // j-blocks (cols 128 each)
#define CPB 128    // cols per block
#define RPB 256    // rows per block

#define NN ((size_t)N * (size_t)N)
#define SLOT ((size_t)N * 4)
#define VTN ((size_t)NPART * N)   // tagged-partial slots per buffer

#define ASU(p, v) __hip_atomic_store((p), (v), __ATOMIC_RELAXED, __HIP_MEMORY_SCOPE_AGENT)
#define ALU(p)    __hip_atomic_load((p), __ATOMIC_RELAXED, __HIP_MEMORY_SCOPE_AGENT)

typedef _Float16 f16x8 __attribute__((ext_vector_type(8)));
typedef float f32x4 __attribute__((ext_vector_type(4)));

// ---------- init: zero d_out, seed tagged triple buffer, zero rc accumulator ----------
__global__ __launch_bounds__(256) void init_kernel(const float* __restrict__ sd,
                                                   unsigned long long* __restrict__ vt,
                                                   float* __restrict__ rcacc,
                                                   float* __restrict__ out) {
    int g = blockIdx.x * 256 + threadIdx.x;          // grid 1536 -> 393216 threads
    if (g < L * 4) out[g] = 0.0f;
    if (g < (int)(3 * VTN)) {
        float val = (g < N) ? sd[g] : 0.0f;          // buf0 partial0 = sd, tag 0
        ASU(&vt[g], (unsigned long long)__float_as_uint(val));
    }
    if (g < 16 * N) rcacc[g] = 0.0f;                 // decoded-rowsum accumulator
}

// ---------- descriptor build ----------
__global__ __launch_bounds__(256) void build_desc_kernel(const int* __restrict__ seq32,
                                                         unsigned char* __restrict__ midx,
                                                         int mode) {
    __shared__ int any_odd;
    if (threadIdx.x == 0) any_odd = 0;
    __syncthreads();
    int acc = 0;
    for (int i = threadIdx.x; i < L / 2; i += 256) acc |= seq32[2 * i + 1];
    if (acc) any_odd = 1;
    __syncthreads();
    const int is64 = (any_odd == 0);
#define SYM(t) ((is64 ? seq32[2 * (t)] : seq32[(t)]) & 1)
    if (mode == 2) {
        for (int k = threadIdx.x; k < L / 4; k += 256)
            midx[k] = (unsigned char)(SYM(4 * k) * 8 + SYM(4 * k + 1) * 4 +
                                      SYM(4 * k + 2) * 2 + SYM(4 * k + 3));
    } else if (mode == 1) {
        for (int k = threadIdx.x; k < L / 2; k += 256)
            midx[k] = (unsigned char)(SYM(2 * k) * 2 + SYM(2 * k + 1));
    } else {
        for (int t = threadIdx.x; t < L; t += 256)
            midx[t] = (unsigned char)SYM(t);
    }
#undef SYM
}

// ---------- softmax over T rows -> fp16 Tm + row-mass correction ----------
__global__ __launch_bounds__(256) void softmax_T_kernel(const float* __restrict__ T,
                                                        unsigned short* __restrict__ Tm,
                                                        float* __restrict__ rowc) {
    int row = blockIdx.x;              // 0..8191 == i*2 + s
    int i = row >> 1, s = row & 1;
    const float* src = T + (size_t)row * N;
    unsigned short* dst = Tm + ((size_t)s << 24) + ((size_t)i << 12);
    int tid = threadIdx.x;

    float vals[16];
    float mx = -1e30f;
#pragma unroll
    for (int k = 0; k < 16; k++) {
        vals[k] = src[tid + (k << 8)];
        mx = fmaxf(mx, vals[k]);
    }
#pragma unroll
    for (int o = 32; o > 0; o >>= 1) mx = fmaxf(mx, __shfl_xor(mx, o));
    __shared__ float red[4];
    int wid = tid >> 6;
    if ((tid & 63) == 0) red[wid] = mx;
    __syncthreads();
    mx = fmaxf(fmaxf(red[0], red[1]), fmaxf(red[2], red[3]));
    __syncthreads();

    float sum = 0.0f;
#pragma unroll
    for (int k = 0; k < 16; k++) {
        vals[k] = __expf(vals[k] - mx);
        sum += vals[k];
    }
#pragma unroll
    for (int o = 32; o > 0; o >>= 1) sum += __shfl_xor(sum, o);
    if ((tid & 63) == 0) red[wid] = sum;
    __syncthreads();
    sum = red[0] + red[1] + red[2] + red[3];
    __syncthreads();
    float inv = 1.0f / sum;

    float qs = 0.0f;
#pragma unroll
    for (int k = 0; k < 16; k++) {
        __half h = __float2half_rn(vals[k] * inv);
        dst[tid + (k << 8)] = __half_as_ushort(h);
        qs += __half2float(h);
    }
#pragma unroll
    for (int o = 32; o > 0; o >>= 1) qs += __shfl_xor(qs, o);
    if ((tid & 63) == 0) red[wid] = qs;
    __syncthreads();
    if (tid == 0) {
        float q = red[0] + red[1] + red[2] + red[3];
        rowc[(size_t)s * N + i] = 1.0f / q;
    }
}

// ---------- softmax over O rows ----------
__global__ __launch_bounds__(256) void softmax_O_kernel(const float* __restrict__ O,
                                                        float* __restrict__ OW) {
    int r = blockIdx.x * 256 + threadIdx.x;
    if (r < 2 * N) {
        float4 x = *(const float4*)(O + (size_t)r * 4);
        float mx = fmaxf(fmaxf(x.x, x.y), fmaxf(x.z, x.w));
        float e0 = __expf(x.x - mx), e1 = __expf(x.y - mx);
        float e2 = __expf(x.z - mx), e3 = __expf(x.w - mx);
        float inv = 1.0f / (e0 + e1 + e2 + e3);
        int i = r >> 1, s = r & 1;
        *(float4*)(OW + (size_t)s * SLOT + (size_t)i * 4) =
            make_float4(e0 * inv, e1 * inv, e2 * inv, e3 * inv);
    }
}

// ---------- fp16 matrix transpose: 64x64 LDS tiles, coalesced both sides ----------
__global__ __launch_bounds__(256) void transpose_kernel(const unsigned short* __restrict__ src,
                                                        unsigned short* __restrict__ dst) {
    int b = blockIdx.x;
    int mat = b >> 12;                 // 4096 tiles per matrix
    int t = b & 4095;
    int ti = t >> 6, tj = t & 63;
    const unsigned short* S = src + (size_t)mat * NN + (size_t)(ti * 64) * N + tj * 64;
    unsigned short* D = dst + (size_t)mat * NN + (size_t)(tj * 64) * N + ti * 64;

    __shared__ unsigned short tile[64][72];   // 72: 16B-aligned rows, conflict-light

    int tid = threadIdx.x;
    int r = tid >> 2, c0 = (tid & 3) * 16;
    *(uint4*)&tile[r][c0]     = *(const uint4*)(S + (size_t)r * N + c0);
    *(uint4*)&tile[r][c0 + 8] = *(const uint4*)(S + (size_t)r * N + c0 + 8);
    __syncthreads();

    int j = tid >> 2, i0 = (tid & 3) * 16;
    unsigned short g[16];
#pragma unroll
    for (int s = 0; s < 16; s++) g[s] = tile[i0 + s][j];
    *(uint4*)(D + (size_t)j * N + i0)     = *(const uint4*)&g[0];
    *(uint4*)(D + (size_t)j * N + i0 + 8) = *(const uint4*)&g[8];
}

// ---------- MFMA GEMM v3: C[pair] = A[pair>>ash] x BT[pair&bmask]^T ----------
// Both operands pre-transposed-as-needed: A row-major, BT = B^T row-major.
// BOTH staged via global_load_lds into linear LDS with XOR-granule swizzle
// (source granule g=(ln&7)^(ln>>3), read granule G=(kk*4+q)^(l15&7)) —
// HW-verified in R18's A path. Zero staging VALU in the K-loop (the old
// B transpose-pack was ~half the per-iter VALU -> ~550 TF ceiling).
// Q8OUT=1: e4m3-style byte out (scale 2^14) + atomic DECODED row sums.
template <int Q8OUT>
__global__ __launch_bounds__(256) void gemm_kernel(const unsigned short* __restrict__ Abase,
                                                   const unsigned short* __restrict__ BTbase,
                                                   void* __restrict__ Cbase,
                                                   float* __restrict__ rcacc,
                                                   int ash, int bmask) {
    const int nwg = gridDim.x;
    int bid0 = blockIdx.x;
    int bid = (bid0 & 7) * (nwg >> 3) + (bid0 >> 3);   // XCD-contiguous remap
    int pair = bid >> 10;
    int tile = bid & 1023;
    int i0 = (tile >> 5) << 7;
    int j0 = (tile & 31) << 7;
    const unsigned short* A  = Abase  + (size_t)(pair >> ash) * NN;
    const unsigned short* BT = BTbase + (size_t)(pair & bmask) * NN;

    __shared__ _Float16 Asd[128 * 64];        // 16 KB linear
    __shared__ _Float16 Bsd[128 * 64];        // 16 KB linear (B^T rows = cols of B)

    const int tid = threadIdx.x;
    const int w = tid >> 6, ln = tid & 63;
    const int wrow = (w >> 1) << 6, wcol = (w & 1) << 6;
    const int q = ln >> 4, l15 = ln & 15;

    const int gA = (ln & 7) ^ (ln >> 3);      // swizzled source granule

    f32x4 acc[4][4] = {};

    for (int k0 = 0; k0 < N; k0 += 64) {
#pragma unroll
        for (int t = 0; t < 4; t++) {
            const int rbase = w * 32 + t * 8;
            const int r = rbase + (ln >> 3);
            __builtin_amdgcn_global_load_lds(
                (const __attribute__((address_space(1))) unsigned int*)
                    (A + (size_t)(i0 + r) * N + k0 + gA * 8),
                (__attribute__((address_space(3))) unsigned int*)(Asd + rbase * 64),
                16, 0, 0);
        }
#pragma unroll
        for (int t = 0; t < 4; t++) {
            const int rbase = w * 32 + t * 8;
            const int r = rbase + (ln >> 3);
            __builtin_amdgcn_global_load_lds(
                (const __attribute__((address_space(1))) unsigned int*)
                    (BT + (size_t)(j0 + r) * N + k0 + gA * 8),
                (__attribute__((address_space(3))) unsigned int*)(Bsd + rbase * 64),
                16, 0, 0);
        }
        __syncthreads();   // drains gl_lds

#pragma unroll
        for (int kk = 0; kk < 2; kk++) {
            f16x8 af[4], bf[4];
#pragma unroll
            for (int ti = 0; ti < 4; ti++) {
                const int R = wrow + ti * 16 + l15;
                const int G = (kk * 4 + q) ^ (l15 & 7);
                af[ti] = *(const f16x8*)(Asd + R * 64 + G * 8);
            }
#pragma unroll
            for (int tj = 0; tj < 4; tj++) {
                const int R = wcol + tj * 16 + l15;
                const int G = (kk * 4 + q) ^ (l15 & 7);
                bf[tj] = *(const f16x8*)(Bsd + R * 64 + G * 8);
            }
#pragma unroll
            for (int ti = 0; ti < 4; ti++)
#pragma unroll
                for (int tj = 0; tj < 4; tj++)
                    acc[ti][tj] = __builtin_amdgcn_mfma_f32_16x16x32_f16(
                        af[ti], bf[tj], acc[ti][tj], 0, 0, 0);
        }
        __syncthreads();
    }

    if (Q8OUT == 0) {
        unsigned short* Pm = (unsigned short*)Cbase + (size_t)pair * NN;
#pragma unroll
        for (int ti = 0; ti < 4; ti++)
#pragma unroll
            for (int tj = 0; tj < 4; tj++)
#pragma unroll
                for (int reg = 0; reg < 4; reg++) {
                    int row = i0 + wrow + ti * 16 + q * 4 + reg;
                    int col = j0 + wcol + tj * 16 + l15;
                    Pm[(size_t)row * N + col] =
                        __half_as_ushort(__float2half_rn(acc[ti][tj][reg]));
                }
    } else {
        unsigned char* Pm8 = (unsigned char*)Cbase + (size_t)pair * NN;
        float* rcrow = rcacc + (size_t)pair * N;
#pragma unroll
        for (int ti = 0; ti < 4; ti++)
#pragma unroll
            for (int reg = 0; reg < 4; reg++) {
                int row = i0 + wrow + ti * 16 + q * 4 + reg;
                float rs = 0.0f;
#pragma unroll
                for (int tj = 0; tj < 4; tj++) {
                    float f = acc[ti][tj][reg] * 16384.0f;
                    unsigned hb = __half_as_ushort(__float2half_rn(f));
                    unsigned r = hb + 0x3Fu + ((hb >> 7) & 1u);   // rn-even into bit7
                    int qv = (int)(r >> 7) - 64;
                    qv = qv < 8 ? 8 : (qv > 0x7E ? 0x7E : qv);
                    unsigned short db = (unsigned short)((qv + 64) << 7);
                    rs += __half2float(*reinterpret_cast<const __half*>(&db));
                    Pm8[(size_t)row * N + j0 + wcol + tj * 16 + l15] = (unsigned char)qv;
                }
                rs += __shfl_xor(rs, 1); rs += __shfl_xor(rs, 2);
                rs += __shfl_xor(rs, 4); rs += __shfl_xor(rs, 8);
                if (l15 == 0) atomicAdd(&rcrow[row], rs);
            }
    }
}

// ---------- invert accumulated decoded row sums -> rc ----------
__global__ __launch_bounds__(256) void rcinv_kernel(float* __restrict__ rc) {
    int g = blockIdx.x * 256 + threadIdx.x;
    if (g < 16 * N) rc[g] = 1.0f / rc[g];
}

// ---------- row sums of fp16 matrices -> rc = 1/sum ----------
__global__ __launch_bounds__(256) void rowsum_kernel(const unsigned short* __restrict__ P,
                                                     float* __restrict__ rc) {
    int b = blockIdx.x;
    const unsigned short* row = P + (size_t)b * N;
    int tid = threadIdx.x;
    const uint4* rp = (const uint4*)row + tid * 2;
    uint4 w0 = rp[0], w1 = rp[1];
    const __half* h0 = (const __half*)&w0;
    const __half* h1 = (const __half*)&w1;
    float s = 0.0f;
#pragma unroll
    for (int j = 0; j < 8; j++) s += __half2float(h0[j]) + __half2float(h1[j]);
#pragma unroll
    for (int o = 32; o > 0; o >>= 1) s += __shfl_xor(s, o);
    __shared__ float red[4];
    if ((tid & 63) == 0) red[tid >> 6] = s;
    __syncthreads();
    if (tid == 0) rc[b] = 1.0f / (red[0] + red[1] + red[2] + red[3]);
}

// ---------- generic N x 4 projection (setup for OW slots) ----------
__global__ __launch_bounds__(256) void proj_kernel(const unsigned short* __restrict__ Tm,
                                                   const unsigned short* __restrict__ P,
                                                   const float* __restrict__ rowc,
                                                   const float* __restrict__ rowc2,
                                                   float* __restrict__ OW, int phase) {
    int bid = blockIdx.x;
    int s = bid >> 12, i = bid & 4095;
    const unsigned short* M; const float* rc; const float* Q; float* dst;
    if (phase == 1) {
        if (s < 4) { M = Tm + (size_t)(s >> 1) * NN; rc = rowc + (size_t)(s >> 1) * N;
                     Q = OW + (size_t)(s & 1) * SLOT; dst = OW + (size_t)(2 + s) * SLOT; }
        else { int q = s - 4; M = P + (size_t)(q >> 1) * NN; rc = rowc2 + (size_t)(q >> 1) * N;
               Q = OW + (size_t)(q & 1) * SLOT; dst = OW + (size_t)(6 + q) * SLOT; }
    } else {
        int q = s; M = P + (size_t)(q >> 2) * NN; rc = rowc2 + (size_t)(q >> 2) * N;
        Q = OW + (size_t)(2 + (q & 3)) * SLOT; dst = OW + (size_t)(14 + q) * SLOT;
    }
    const unsigned short* row = M + (size_t)i * N;
    int tid = threadIdx.x;
    const uint4* rp = (const uint4*)row + tid * 2;
    uint4 w0 = rp[0], w1 = rp[1];
    const __half* h0 = (const __half*)&w0;
    const __half* h1 = (const __half*)&w1;
    int j0 = tid * 16;
    float ac[4] = {};
#pragma unroll
    for (int j = 0; j < 8; j++) {
        float tv = __half2float(h0[j]);
        float4 o = *(const float4*)(Q + (size_t)(j0 + j) * 4);
        ac[0] += tv * o.x; ac[1] += tv * o.y; ac[2] += tv * o.z; ac[3] += tv * o.w;
        float tv1 = __half2float(h1[j]);
        float4 o1 = *(const float4*)(Q + (size_t)(j0 + 8 + j) * 4);
        ac[0] += tv1 * o1.x; ac[1] += tv1 * o1.y; ac[2] += tv1 * o1.z; ac[3] += tv1 * o1.w;
    }
#pragma unroll
    for (int e = 0; e < 4; e++)
#pragma unroll
        for (int o = 32; o > 0; o >>= 1) ac[e] += __shfl_xor(ac[e], o);
    __shared__ float red[4][4];
    if ((tid & 63) == 0)
#pragma unroll
        for (int e = 0; e < 4; e++) red[tid >> 6][e] = ac[e];
    __syncthreads();
    if (tid < 4)
        dst[(size_t)i * 4 + tid] =
            (red[0][tid] + red[1][tid] + red[2][tid] + red[3][tid]) * rc[i];
}

// ---------- decode helper: 2 quant bytes -> float2 via fp16 bit trick ----------
__device__ __forceinline__ float2 d8x2(unsigned b0, unsigned b1) {
    unsigned pk = ((b0 + 64u) << 7) | ((b1 + 64u) << 23);
    return __half22float2(*reinterpret_cast<__half2*>(&pk));
}

// ---------- spin: wait until my 16 partials carry tag==k, sum them (R16) ----------
#define SPIN_SUM(vinp, kk, accv)                                               \
    {                                                                          \
        unsigned long long uv[16];                                             \
        _Pragma("unroll")                                                      \
        for (int p = 0; p < 16; p++) uv[p] = ALU((vinp) + p * N);              \
        unsigned miss = 0;                                                     \
        _Pragma("unroll")                                                      \
        for (int p = 0; p < 16; p++)                                           \
            if ((unsigned)(uv[p] >> 32) != (kk)) miss |= 1u << p;              \
        while (__builtin_expect(miss != 0, 0)) {                               \
            _Pragma("unroll")                                                  \
            for (int p = 0; p < 16; p++)                                       \
                if (miss & (1u << p)) {                                        \
                    unsigned long long t = ALU((vinp) + p * N);                \
                    if ((unsigned)(t >> 32) == (kk)) { uv[p] = t; miss &= ~(1u << p); } \
                }                                                              \
        }                                                                      \
        _Pragma("unroll")                                                      \
        for (int p = 0; p < 16; p++) accv += __uint_as_float((unsigned)uv[p]); \
    }

// ================== fp8 scan (mode 3) — R16 schedule (measured best) ==================
__global__ __launch_bounds__(256, 2) void scan8_kernel(const unsigned char* __restrict__ Q8,
                                                       const float* __restrict__ rc,
                                                       const float* __restrict__ OW,
                                                       const unsigned char* __restrict__ midx,
                                                       unsigned long long* __restrict__ vt,
                                                       float* __restrict__ out,
                                                       int S, int OPS) {
    const int tid = threadIdx.x;
    const int jb = blockIdx.x & 31;
    const int ic = blockIdx.x >> 5;      // 0..15
    const int i0 = ic * RPB;
    const int j0 = jb * CPB;

    __shared__ unsigned char mt8[2][RPB][CPB];   // 2 x 32 KiB fp8 tile
    __shared__ float v[RPB];
    __shared__ float vc[RPB];
    __shared__ float colacc[CPB];

    const int cg = tid & 15;
    const int rg = tid >> 4;

    const int w4 = tid >> 6;
    const int ln = tid & 63;
    const size_t goff8 = (size_t)(i0 + (ln >> 3)) * N + j0 + (ln & 7) * 16;

#define STAGE8(Mb, dst)                                                         \
    _Pragma("unroll")                                                           \
    for (int t = 0; t < 8; t++) {                                               \
        const int row0 = w4 * 64 + t * 8;                                       \
        __builtin_amdgcn_global_load_lds(                                       \
            (const __attribute__((address_space(1))) unsigned int*)((Mb) + goff8 + (size_t)row0 * N), \
            (__attribute__((address_space(3))) unsigned int*)((dst) + (size_t)row0 * CPB),            \
            16, 0, 0);                                                          \
    }

    int mcur = (int)midx[0];
    int mnxt = (S > 1) ? (int)midx[1] : 0;
    float rc_cur = rc[(size_t)mcur * N + i0 + tid];
    float rc_nxt = (S > 1) ? rc[(size_t)mnxt * N + i0 + tid] : 0.0f;
    STAGE8(Q8 + (size_t)mcur * NN, &mt8[0][0][0]);

    for (int k = 0; k < S; k++) {
        const int m = mcur;
        const unsigned long long* vinp = vt + (size_t)(k % 3) * VTN + (i0 + tid);
        unsigned long long* voutp = vt + (size_t)((k + 1) % 3) * VTN + (size_t)ic * N + j0;
        const unsigned char* mtc = &mt8[k & 1][0][0];

        float accv = 0.0f;
        SPIN_SUM(vinp, (unsigned)k, accv);
        v[tid] = accv;
        vc[tid] = accv * rc_cur;
        if (tid < CPB) colacc[tid] = 0.0f;

        if (k + 1 < S) {
            STAGE8(Q8 + (size_t)mnxt * NN, &mt8[(k + 1) & 1][0][0]);
            asm volatile("s_waitcnt vmcnt(8) lgkmcnt(0)" ::: "memory");
        } else {
            asm volatile("s_waitcnt vmcnt(0) lgkmcnt(0)" ::: "memory");
        }
        __builtin_amdgcn_s_barrier();
        __builtin_amdgcn_sched_barrier(0);

        float a[8];
#pragma unroll
        for (int e = 0; e < 8; e++) a[e] = 0.0f;
#pragma unroll
        for (int r = 0; r < 16; r++) {
            uint2 w = *(const uint2*)(mtc + (size_t)(rg * 16 + r) * CPB + cg * 8);
            float vi = vc[rg * 16 + r];
            float2 f0 = d8x2(w.x & 0xFF, (w.x >> 8) & 0xFF);
            float2 f1 = d8x2((w.x >> 16) & 0xFF, w.x >> 24);
            float2 f2 = d8x2(w.y & 0xFF, (w.y >> 8) & 0xFF);
            float2 f3 = d8x2((w.y >> 16) & 0xFF, w.y >> 24);
            a[0] += vi * f0.x; a[1] += vi * f0.y;
            a[2] += vi * f1.x; a[3] += vi * f1.y;
            a[4] += vi * f2.x; a[5] += vi * f2.y;
            a[6] += vi * f3.x; a[7] += vi * f3.y;
        }
#pragma unroll
        for (int e = 0; e < 8; e++) atomicAdd(&colacc[cg * 8 + e], a[e]);

        if (jb < OPS) {
            int slot;
            if (OPS == 4) slot = (jb == 0) ? (m >> 3) : (jb == 1) ? 2 + (m >> 2)
                               : (jb == 2) ? 6 + (m >> 1) : 14 + m;
            else if (OPS == 2) slot = (jb == 0) ? (m >> 1) : 2 + m;
            else slot = m;
            const float* pr = OW + (size_t)slot * SLOT;
            int r = tid >> 2, c = tid & 3;
            float p = v[r]       * pr[(size_t)(i0 + r) * 4 + c]
                    + v[r + 64]  * pr[(size_t)(i0 + r + 64) * 4 + c]
                    + v[r + 128] * pr[(size_t)(i0 + r + 128) * 4 + c]
                    + v[r + 192] * pr[(size_t)(i0 + r + 192) * 4 + c];
            p += __shfl_down(p, 32); p += __shfl_down(p, 16);
            p += __shfl_down(p, 8);  p += __shfl_down(p, 4);
            if ((tid & 63) < 4) atomicAdd(&out[(k * OPS + jb) * 4 + (tid & 3)], p);
        }

        asm volatile("s_waitcnt lgkmcnt(0)" ::: "memory");
        __builtin_amdgcn_s_barrier();
        __builtin_amdgcn_sched_barrier(0);

        if (tid < CPB) {
            unsigned long long pk = ((unsigned long long)(unsigned)(k + 1) << 32)
                                  | (unsigned long long)__float_as_uint(colacc[tid]);
            ASU(&voutp[tid], pk);
        }
        mcur = mnxt; rc_cur = rc_nxt;
        if (k + 2 < S) {
            mnxt = (int)midx[k + 2];
            rc_nxt = rc[(size_t)mnxt * N + i0 + tid];
        }
    }
#undef STAGE8
}

// ================== fp16 scan fallback (modes 0/1), tagged sync ==================
__global__ __launch_bounds__(256, 2) void scan16_kernel(const unsigned short* __restrict__ Mbase,
                                                        const float* __restrict__ rc,
                                                        const float* __restrict__ OW,
                                                        const unsigned char* __restrict__ midx,
                                                        unsigned long long* __restrict__ vt,
                                                        float* __restrict__ out,
                                                        int S, int OPS) {
    const int tid = threadIdx.x;
    const int jb = blockIdx.x & 31;
    const int ic = blockIdx.x >> 5;
    const int i0 = ic * RPB;
    const int j0 = jb * CPB;

    __shared__ unsigned short mt[RPB][CPB];
    __shared__ float v[RPB];
    __shared__ float vc[RPB];
    __shared__ float colacc[CPB];

    const int cg = tid & 15;
    const int rg = tid >> 4;

    const int w4 = tid >> 6;
    const int ln = tid & 63;
    const size_t goff = (size_t)(i0 + (ln >> 4)) * N + j0 + (ln & 15) * 8;

    int mcur = (int)midx[0];
    int mnxt = (S > 1) ? (int)midx[1] : 0;
    float rc_cur = rc[(size_t)mcur * N + i0 + tid];
    float rc_nxt = (S > 1) ? rc[(size_t)mnxt * N + i0 + tid] : 0.0f;
    {
        const unsigned short* Mb = Mbase + (size_t)mcur * NN;
#pragma unroll
        for (int t = 0; t < 16; t++) {
            const int row0 = w4 * 64 + t * 4;
            __builtin_amdgcn_global_load_lds(
                (const __attribute__((address_space(1))) unsigned int*)(Mb + goff + (size_t)row0 * N),
                (__attribute__((address_space(3))) unsigned int*)(&mt[row0][0]),
                16, 0, 0);
        }
    }

    for (int k = 0; k < S; k++) {
        const int m = mcur;
        const unsigned long long* vinp = vt + (size_t)(k % 3) * VTN + (i0 + tid);
        unsigned long long* voutp = vt + (size_t)((k + 1) % 3) * VTN + (size_t)ic * N + j0;

        float accv = 0.0f;
        SPIN_SUM(vinp, (unsigned)k, accv);
        v[tid] = accv;
        vc[tid] = accv * rc_cur;
        if (tid < CPB) colacc[tid] = 0.0f;
        __syncthreads();

        float a[8];
#pragma unroll
        for (int e = 0; e < 8; e++) a[e] = 0.0f;
#pragma unroll
        for (int r = 0; r < 16; r++) {
            uint4 w = *(const uint4*)&mt[rg * 16 + r][cg * 8];
            float vi = vc[rg * 16 + r];
            float2 f0 = __half22float2(*(__half2*)&w.x);
            float2 f1 = __half22float2(*(__half2*)&w.y);
            float2 f2 = __half22float2(*(__half2*)&w.z);
            float2 f3 = __half22float2(*(__half2*)&w.w);
            a[0] += vi * f0.x; a[1] += vi * f0.y;
            a[2] += vi * f1.x; a[3] += vi * f1.y;
            a[4] += vi * f2.x; a[5] += vi * f2.y;
            a[6] += vi * f3.x; a[7] += vi * f3.y;
        }
#pragma unroll
        for (int e = 0; e < 8; e++) atomicAdd(&colacc[cg * 8 + e], a[e]);

        if (jb < OPS) {
            int slot;
            if (OPS == 4) slot = (jb == 0) ? (m >> 3) : (jb == 1) ? 2 + (m >> 2)
                               : (jb == 2) ? 6 + (m >> 1) : 14 + m;
            else if (OPS == 2) slot = (jb == 0) ? (m >> 1) : 2 + m;
            else slot = m;
            const float* pr = OW + (size_t)slot * SLOT;
            int r = tid >> 2, c = tid & 3;
            float p = v[r]       * pr[(size_t)(i0 + r) * 4 + c]
                    + v[r + 64]  * pr[(size_t)(i0 + r + 64) * 4 + c]
                    + v[r + 128] * pr[(size_t)(i0 + r + 128) * 4 + c]
                    + v[r + 192] * pr[(size_t)(i0 + r + 192) * 4 + c];
            p += __shfl_down(p, 32); p += __shfl_down(p, 16);
            p += __shfl_down(p, 8);  p += __shfl_down(p, 4);
            if ((tid & 63) < 4) atomicAdd(&out[(k * OPS + jb) * 4 + (tid & 3)], p);
        }
        __syncthreads();

        if (tid < CPB) {
            unsigned long long pk = ((unsigned long long)(unsigned)(k + 1) << 32)
                                  | (unsigned long long)__float_as_uint(colacc[tid]);
            ASU(&voutp[tid], pk);
        }
        if (k + 1 < S) {
            const unsigned short* Mb = Mbase + (size_t)mnxt * NN;
#pragma unroll
            for (int t = 0; t < 16; t++) {
                const int row0 = w4 * 64 + t * 4;
                __builtin_amdgcn_global_load_lds(
                    (const __attribute__((address_space(1))) unsigned int*)(Mb + goff + (size_t)row0 * N),
                    (__attribute__((address_space(3))) unsigned int*)(&mt[row0][0]),
                    16, 0, 0);
            }
        }
        mcur = mnxt; rc_cur = rc_nxt;
        if (k + 2 < S) {
            mnxt = (int)midx[k + 2];
            rc_nxt = rc[(size_t)mnxt * N + i0 + tid];
        }
    }
}

extern "C" void kernel_launch(void* const* d_in, const int* in_sizes, int n_in,
                              void* d_out, int out_size, void* d_ws, size_t ws_size,
                              hipStream_t stream) {
    const float* sd  = (const float*)d_in[0];   // [4096]
    const int*   seq = (const int*)d_in[1];     // [4096]
    const float* T   = (const float*)d_in[2];   // [4096,2,4096]
    const float* O   = (const float*)d_in[3];   // [4096,2,4]
    float* out = (float*)d_out;                 // [4096,4]

    const size_t TM_SZ = 2 * NN * 2;            // 64 MiB
    const size_t P_SZ  = 4 * NN * 2;            // 128 MiB
    const size_t Q8_SZ = 16 * NN;               // 256 MiB fp8 matrices
    const size_t AUX_SZ = 0x400000;             // 4 MiB aux block

    // mode 3: Tm + TmT + P + PT + Q8 + aux = 644 MiB
    int mode = (ws_size >= 2 * TM_SZ + 2 * P_SZ + Q8_SZ + AUX_SZ) ? 3
             : (ws_size >= 2 * TM_SZ + P_SZ + AUX_SZ) ? 1 : 0;

    char* ws = (char*)d_ws;
    unsigned short* Tm  = (unsigned short*)ws;
    unsigned short* TmT = (unsigned short*)(ws + TM_SZ);
    unsigned short* P   = (unsigned short*)(ws + 2 * TM_SZ);
    unsigned short* PT  = (unsigned short*)(ws + 2 * TM_SZ + P_SZ);
    unsigned char*  Q8  = (unsigned char*)(ws + 2 * TM_SZ + 2 * P_SZ);
    char* aux = ws + (mode == 3 ? 2 * TM_SZ + 2 * P_SZ + Q8_SZ
                    : mode == 1 ? 2 * TM_SZ + P_SZ : TM_SZ);
    float* rowc   = (float*)(aux);               // 32 KB
    float* rowc2  = (float*)(aux + 0x8000);      // 64 KB
    float* rowc4  = (float*)(aux + 0x18000);     // 256 KB (rcacc -> rc in mode 3)
    float* OW     = (float*)(aux + 0x58000);     // 32 slots x 64 KB = 2 MB
    unsigned long long* vt = (unsigned long long*)(aux + 0x258000);  // 1.5 MiB tagged partials
    unsigned char* midx = (unsigned char*)(aux + 0x3D8000);

    hipLaunchKernelGGL(init_kernel, dim3(1536), dim3(256), 0, stream, sd, vt, rowc4, out);
    hipLaunchKernelGGL(build_desc_kernel, dim3(1), dim3(256), 0, stream, seq, midx,
                       mode == 3 ? 2 : mode);
    hipLaunchKernelGGL(softmax_T_kernel, dim3(2 * N), dim3(256), 0, stream, T, Tm, rowc);
    hipLaunchKernelGGL(softmax_O_kernel, dim3(32), dim3(256), 0, stream, O, OW);

    if (mode == 3) {
        hipLaunchKernelGGL(transpose_kernel, dim3(2 * 4096), dim3(256), 0, stream, Tm, TmT);
        hipLaunchKernelGGL(HIP_KERNEL_NAME(gemm_kernel<0>), dim3(4 * 1024), dim3(256), 0, stream,
                           Tm, TmT, (void*)P, rowc4, 1, 1);
        hipLaunchKernelGGL(rowsum_kernel, dim3(4 * N), dim3(256), 0, stream, P, rowc2);
        hipLaunchKernelGGL(transpose_kernel, dim3(4 * 4096), dim3(256), 0, stream, P, PT);
        hipLaunchKernelGGL(HIP_KERNEL_NAME(gemm_kernel<1>), dim3(16 * 1024), dim3(256), 0, stream,
                           P, PT, (void*)Q8, rowc4, 2, 3);
        hipLaunchKernelGGL(rcinv_kernel, dim3(256), dim3(256), 0, stream, rowc4);
        hipLaunchKernelGGL(proj_kernel, dim3(12 * N), dim3(256), 0, stream, Tm, P, rowc, rowc2, OW, 1);
        hipLaunchKernelGGL(proj_kernel, dim3(16 * N), dim3(256), 0, stream, Tm, P, rowc, rowc2, OW, 2);
        hipLaunchKernelGGL(scan8_kernel, dim3(512), dim3(256), 0, stream,
                           Q8, rowc4, OW, midx, vt, out, L / 4, 4);
    } else if (mode == 1) {
        hipLaunchKernelGGL(transpose_kernel, dim3(2 * 4096), dim3(256), 0, stream, Tm, TmT);
        hipLaunchKernelGGL(HIP_KERNEL_NAME(gemm_kernel<0>), dim3(4 * 1024), dim3(256), 0, stream,
                           Tm, TmT, (void*)P, rowc4, 1, 1);
        hipLaunchKernelGGL(rowsum_kernel, dim3(4 * N), dim3(256), 0, stream, P, rowc2);
        hipLaunchKernelGGL(proj_kernel, dim3(4 * N), dim3(256), 0, stream, Tm, P, rowc, rowc2, OW, 1);
        hipLaunchKernelGGL(scan16_kernel, dim3(512), dim3(256), 0, stream,
                           P, rowc2, OW, midx, vt, out, L / 2, 2);
    } else {
        hipLaunchKernelGGL(scan16_kernel, dim3(512), dim3(256), 0, stream,
                           Tm, rowc, OW, midx, vt, out, L, 1);
    }
}

// Round 11
// 14500.732 us; speedup vs baseline: 1.3883x; 1.3883x over previous
//
#include <hip/hip_runtime.h>
#include <hip/hip_fp16.h>

#define N 4096
#define L 4096
#define NPART 16   // i-chunks (rows 256 each)
#define NJB 32     // j-blocks (cols 128 each)
#define CPB 128    // cols per block
#define RPB 256    // rows per block

#define NN ((size_t)N * (size_t)N)
#define SLOT ((size_t)N * 4)
#define VTN ((size_t)NPART * N)   // tagged-partial slots per buffer

#define ASU(p, v) __hip_atomic_store((p), (v), __ATOMIC_RELAXED, __HIP_MEMORY_SCOPE_AGENT)
#define ALU(p)    __hip_atomic_load((p), __ATOMIC_RELAXED, __HIP_MEMORY_SCOPE_AGENT)

typedef _Float16 f16x8 __attribute__((ext_vector_type(8)));
typedef float f32x4 __attribute__((ext_vector_type(4)));

// ---------- init: zero d_out, seed tagged triple buffer, zero rc accumulator ----------
__global__ __launch_bounds__(256) void init_kernel(const float* __restrict__ sd,
                                                   unsigned long long* __restrict__ vt,
                                                   float* __restrict__ rcacc,
                                                   float* __restrict__ out) {
    int g = blockIdx.x * 256 + threadIdx.x;          // grid 1536 -> 393216 threads
    if (g < L * 4) out[g] = 0.0f;
    if (g < (int)(3 * VTN)) {
        float val = (g < N) ? sd[g] : 0.0f;          // buf0 partial0 = sd, tag 0
        ASU(&vt[g], (unsigned long long)__float_as_uint(val));
    }
    if (g < 16 * N) rcacc[g] = 0.0f;                 // decoded-rowsum accumulator
}

// ---------- descriptor build ----------
__global__ __launch_bounds__(256) void build_desc_kernel(const int* __restrict__ seq32,
                                                         unsigned char* __restrict__ midx,
                                                         int mode) {
    __shared__ int any_odd;
    if (threadIdx.x == 0) any_odd = 0;
    __syncthreads();
    int acc = 0;
    for (int i = threadIdx.x; i < L / 2; i += 256) acc |= seq32[2 * i + 1];
    if (acc) any_odd = 1;
    __syncthreads();
    const int is64 = (any_odd == 0);
#define SYM(t) ((is64 ? seq32[2 * (t)] : seq32[(t)]) & 1)
    if (mode == 2) {
        for (int k = threadIdx.x; k < L / 4; k += 256)
            midx[k] = (unsigned char)(SYM(4 * k) * 8 + SYM(4 * k + 1) * 4 +
                                      SYM(4 * k + 2) * 2 + SYM(4 * k + 3));
    } else if (mode == 1) {
        for (int k = threadIdx.x; k < L / 2; k += 256)
            midx[k] = (unsigned char)(SYM(2 * k) * 2 + SYM(2 * k + 1));
    } else {
        for (int t = threadIdx.x; t < L; t += 256)
            midx[t] = (unsigned char)SYM(t);
    }
#undef SYM
}

// ---------- softmax over T rows -> fp16 Tm + row-mass correction ----------
__global__ __launch_bounds__(256) void softmax_T_kernel(const float* __restrict__ T,
                                                        unsigned short* __restrict__ Tm,
                                                        float* __restrict__ rowc) {
    int row = blockIdx.x;              // 0..8191 == i*2 + s
    int i = row >> 1, s = row & 1;
    const float* src = T + (size_t)row * N;
    unsigned short* dst = Tm + ((size_t)s << 24) + ((size_t)i << 12);
    int tid = threadIdx.x;

    float vals[16];
    float mx = -1e30f;
#pragma unroll
    for (int k = 0; k < 16; k++) {
        vals[k] = src[tid + (k << 8)];
        mx = fmaxf(mx, vals[k]);
    }
#pragma unroll
    for (int o = 32; o > 0; o >>= 1) mx = fmaxf(mx, __shfl_xor(mx, o));
    __shared__ float red[4];
    int wid = tid >> 6;
    if ((tid & 63) == 0) red[wid] = mx;
    __syncthreads();
    mx = fmaxf(fmaxf(red[0], red[1]), fmaxf(red[2], red[3]));
    __syncthreads();

    float sum = 0.0f;
#pragma unroll
    for (int k = 0; k < 16; k++) {
        vals[k] = __expf(vals[k] - mx);
        sum += vals[k];
    }
#pragma unroll
    for (int o = 32; o > 0; o >>= 1) sum += __shfl_xor(sum, o);
    if ((tid & 63) == 0) red[wid] = sum;
    __syncthreads();
    sum = red[0] + red[1] + red[2] + red[3];
    __syncthreads();
    float inv = 1.0f / sum;

    float qs = 0.0f;
#pragma unroll
    for (int k = 0; k < 16; k++) {
        __half h = __float2half_rn(vals[k] * inv);
        dst[tid + (k << 8)] = __half_as_ushort(h);
        qs += __half2float(h);
    }
#pragma unroll
    for (int o = 32; o > 0; o >>= 1) qs += __shfl_xor(qs, o);
    if ((tid & 63) == 0) red[wid] = qs;
    __syncthreads();
    if (tid == 0) {
        float q = red[0] + red[1] + red[2] + red[3];
        rowc[(size_t)s * N + i] = 1.0f / q;
    }
}

// ---------- softmax over O rows ----------
__global__ __launch_bounds__(256) void softmax_O_kernel(const float* __restrict__ O,
                                                        float* __restrict__ OW) {
    int r = blockIdx.x * 256 + threadIdx.x;
    if (r < 2 * N) {
        float4 x = *(const float4*)(O + (size_t)r * 4);
        float mx = fmaxf(fmaxf(x.x, x.y), fmaxf(x.z, x.w));
        float e0 = __expf(x.x - mx), e1 = __expf(x.y - mx);
        float e2 = __expf(x.z - mx), e3 = __expf(x.w - mx);
        float inv = 1.0f / (e0 + e1 + e2 + e3);
        int i = r >> 1, s = r & 1;
        *(float4*)(OW + (size_t)s * SLOT + (size_t)i * 4) =
            make_float4(e0 * inv, e1 * inv, e2 * inv, e3 * inv);
    }
}

// ---------- fp16 single-matrix transpose: 64x64 LDS tiles, grid 4096 ----------
__global__ __launch_bounds__(256) void transpose_kernel(const unsigned short* __restrict__ S0,
                                                        unsigned short* __restrict__ D0) {
    int b = blockIdx.x;                // 0..4095
    int ti = b >> 6, tj = b & 63;
    const unsigned short* S = S0 + (size_t)(ti * 64) * N + tj * 64;
    unsigned short* D = D0 + (size_t)(tj * 64) * N + ti * 64;

    __shared__ unsigned short tile[64][72];

    int tid = threadIdx.x;
    int r = tid >> 2, c0 = (tid & 3) * 16;
    *(uint4*)&tile[r][c0]     = *(const uint4*)(S + (size_t)r * N + c0);
    *(uint4*)&tile[r][c0 + 8] = *(const uint4*)(S + (size_t)r * N + c0 + 8);
    __syncthreads();

    int j = tid >> 2, i0 = (tid & 3) * 16;
    unsigned short g[16];
#pragma unroll
    for (int s = 0; s < 16; s++) g[s] = tile[i0 + s][j];
    *(uint4*)(D + (size_t)j * N + i0)     = *(const uint4*)&g[0];
    *(uint4*)(D + (size_t)j * N + i0 + 8) = *(const uint4*)&g[8];
}

// ---------- MFMA GEMM v3 (HW-verified R19 mode 1): C = A[p] x BT^T ----------
// A = Abase + p*NN (p = sub-launch pair id); BT = single pre-transposed
// matrix (32 MiB TB buffer); C matrix index = cidx_base + p*cidx_stride.
// Both operands staged via global_load_lds, XOR-granule swizzle both sides.
// Q8OUT=1: e4m3-style byte out (scale 2^14) + atomic DECODED row sums.
template <int Q8OUT>
__global__ __launch_bounds__(256) void gemm_kernel(const unsigned short* __restrict__ Abase,
                                                   const unsigned short* __restrict__ BT,
                                                   void* __restrict__ Cbase,
                                                   float* __restrict__ rcacc,
                                                   int cidx_base, int cidx_stride) {
    const int nwg = gridDim.x;
    int bid0 = blockIdx.x;
    int bid = (bid0 & 7) * (nwg >> 3) + (bid0 >> 3);   // XCD-contiguous remap
    int pair = bid >> 10;
    int tile = bid & 1023;
    int i0 = (tile >> 5) << 7;
    int j0 = (tile & 31) << 7;
    const unsigned short* A = Abase + (size_t)pair * NN;
    const int cidx = cidx_base + pair * cidx_stride;

    __shared__ _Float16 Asd[128 * 64];        // 16 KB linear
    __shared__ _Float16 Bsd[128 * 64];        // 16 KB linear

    const int tid = threadIdx.x;
    const int w = tid >> 6, ln = tid & 63;
    const int wrow = (w >> 1) << 6, wcol = (w & 1) << 6;
    const int q = ln >> 4, l15 = ln & 15;

    const int gA = (ln & 7) ^ (ln >> 3);      // swizzled source granule

    f32x4 acc[4][4] = {};

    for (int k0 = 0; k0 < N; k0 += 64) {
#pragma unroll
        for (int t = 0; t < 4; t++) {
            const int rbase = w * 32 + t * 8;
            const int r = rbase + (ln >> 3);
            __builtin_amdgcn_global_load_lds(
                (const __attribute__((address_space(1))) unsigned int*)
                    (A + (size_t)(i0 + r) * N + k0 + gA * 8),
                (__attribute__((address_space(3))) unsigned int*)(Asd + rbase * 64),
                16, 0, 0);
        }
#pragma unroll
        for (int t = 0; t < 4; t++) {
            const int rbase = w * 32 + t * 8;
            const int r = rbase + (ln >> 3);
            __builtin_amdgcn_global_load_lds(
                (const __attribute__((address_space(1))) unsigned int*)
                    (BT + (size_t)(j0 + r) * N + k0 + gA * 8),
                (__attribute__((address_space(3))) unsigned int*)(Bsd + rbase * 64),
                16, 0, 0);
        }
        __syncthreads();   // drains gl_lds

#pragma unroll
        for (int kk = 0; kk < 2; kk++) {
            f16x8 af[4], bf[4];
#pragma unroll
            for (int ti = 0; ti < 4; ti++) {
                const int R = wrow + ti * 16 + l15;
                const int G = (kk * 4 + q) ^ (l15 & 7);
                af[ti] = *(const f16x8*)(Asd + R * 64 + G * 8);
            }
#pragma unroll
            for (int tj = 0; tj < 4; tj++) {
                const int R = wcol + tj * 16 + l15;
                const int G = (kk * 4 + q) ^ (l15 & 7);
                bf[tj] = *(const f16x8*)(Bsd + R * 64 + G * 8);
            }
#pragma unroll
            for (int ti = 0; ti < 4; ti++)
#pragma unroll
                for (int tj = 0; tj < 4; tj++)
                    acc[ti][tj] = __builtin_amdgcn_mfma_f32_16x16x32_f16(
                        af[ti], bf[tj], acc[ti][tj], 0, 0, 0);
        }
        __syncthreads();
    }

    if (Q8OUT == 0) {
        unsigned short* Pm = (unsigned short*)Cbase + (size_t)cidx * NN;
#pragma unroll
        for (int ti = 0; ti < 4; ti++)
#pragma unroll
            for (int tj = 0; tj < 4; tj++)
#pragma unroll
                for (int reg = 0; reg < 4; reg++) {
                    int row = i0 + wrow + ti * 16 + q * 4 + reg;
                    int col = j0 + wcol + tj * 16 + l15;
                    Pm[(size_t)row * N + col] =
                        __half_as_ushort(__float2half_rn(acc[ti][tj][reg]));
                }
    } else {
        unsigned char* Pm8 = (unsigned char*)Cbase + (size_t)cidx * NN;
        float* rcrow = rcacc + (size_t)cidx * N;
#pragma unroll
        for (int ti = 0; ti < 4; ti++)
#pragma unroll
            for (int reg = 0; reg < 4; reg++) {
                int row = i0 + wrow + ti * 16 + q * 4 + reg;
                float rs = 0.0f;
#pragma unroll
                for (int tj = 0; tj < 4; tj++) {
                    float f = acc[ti][tj][reg] * 16384.0f;
                    unsigned hb = __half_as_ushort(__float2half_rn(f));
                    unsigned r = hb + 0x3Fu + ((hb >> 7) & 1u);   // rn-even into bit7
                    int qv = (int)(r >> 7) - 64;
                    qv = qv < 8 ? 8 : (qv > 0x7E ? 0x7E : qv);
                    unsigned short db = (unsigned short)((qv + 64) << 7);
                    rs += __half2float(*reinterpret_cast<const __half*>(&db));
                    Pm8[(size_t)row * N + j0 + wcol + tj * 16 + l15] = (unsigned char)qv;
                }
                rs += __shfl_xor(rs, 1); rs += __shfl_xor(rs, 2);
                rs += __shfl_xor(rs, 4); rs += __shfl_xor(rs, 8);
                if (l15 == 0) atomicAdd(&rcrow[row], rs);
            }
    }
}

// ---------- invert accumulated decoded row sums -> rc ----------
__global__ __launch_bounds__(256) void rcinv_kernel(float* __restrict__ rc) {
    int g = blockIdx.x * 256 + threadIdx.x;
    if (g < 16 * N) rc[g] = 1.0f / rc[g];
}

// ---------- row sums of fp16 matrices -> rc = 1/sum ----------
__global__ __launch_bounds__(256) void rowsum_kernel(const unsigned short* __restrict__ P,
                                                     float* __restrict__ rc) {
    int b = blockIdx.x;
    const unsigned short* row = P + (size_t)b * N;
    int tid = threadIdx.x;
    const uint4* rp = (const uint4*)row + tid * 2;
    uint4 w0 = rp[0], w1 = rp[1];
    const __half* h0 = (const __half*)&w0;
    const __half* h1 = (const __half*)&w1;
    float s = 0.0f;
#pragma unroll
    for (int j = 0; j < 8; j++) s += __half2float(h0[j]) + __half2float(h1[j]);
#pragma unroll
    for (int o = 32; o > 0; o >>= 1) s += __shfl_xor(s, o);
    __shared__ float red[4];
    if ((tid & 63) == 0) red[tid >> 6] = s;
    __syncthreads();
    if (tid == 0) rc[b] = 1.0f / (red[0] + red[1] + red[2] + red[3]);
}

// ---------- generic N x 4 projection (setup for OW slots) ----------
__global__ __launch_bounds__(256) void proj_kernel(const unsigned short* __restrict__ Tm,
                                                   const unsigned short* __restrict__ P,
                                                   const float* __restrict__ rowc,
                                                   const float* __restrict__ rowc2,
                                                   float* __restrict__ OW, int phase) {
    int bid = blockIdx.x;
    int s = bid >> 12, i = bid & 4095;
    const unsigned short* M; const float* rc; const float* Q; float* dst;
    if (phase == 1) {
        if (s < 4) { M = Tm + (size_t)(s >> 1) * NN; rc = rowc + (size_t)(s >> 1) * N;
                     Q = OW + (size_t)(s & 1) * SLOT; dst = OW + (size_t)(2 + s) * SLOT; }
        else { int q = s - 4; M = P + (size_t)(q >> 1) * NN; rc = rowc2 + (size_t)(q >> 1) * N;
               Q = OW + (size_t)(q & 1) * SLOT; dst = OW + (size_t)(6 + q) * SLOT; }
    } else {
        int q = s; M = P + (size_t)(q >> 2) * NN; rc = rowc2 + (size_t)(q >> 2) * N;
        Q = OW + (size_t)(2 + (q & 3)) * SLOT; dst = OW + (size_t)(14 + q) * SLOT;
    }
    const unsigned short* row = M + (size_t)i * N;
    int tid = threadIdx.x;
    const uint4* rp = (const uint4*)row + tid * 2;
    uint4 w0 = rp[0], w1 = rp[1];
    const __half* h0 = (const __half*)&w0;
    const __half* h1 = (const __half*)&w1;
    int j0 = tid * 16;
    float ac[4] = {};
#pragma unroll
    for (int j = 0; j < 8; j++) {
        float tv = __half2float(h0[j]);
        float4 o = *(const float4*)(Q + (size_t)(j0 + j) * 4);
        ac[0] += tv * o.x; ac[1] += tv * o.y; ac[2] += tv * o.z; ac[3] += tv * o.w;
        float tv1 = __half2float(h1[j]);
        float4 o1 = *(const float4*)(Q + (size_t)(j0 + 8 + j) * 4);
        ac[0] += tv1 * o1.x; ac[1] += tv1 * o1.y; ac[2] += tv1 * o1.z; ac[3] += tv1 * o1.w;
    }
#pragma unroll
    for (int e = 0; e < 4; e++)
#pragma unroll
        for (int o = 32; o > 0; o >>= 1) ac[e] += __shfl_xor(ac[e], o);
    __shared__ float red[4][4];
    if ((tid & 63) == 0)
#pragma unroll
        for (int e = 0; e < 4; e++) red[tid >> 6][e] = ac[e];
    __syncthreads();
    if (tid < 4)
        dst[(size_t)i * 4 + tid] =
            (red[0][tid] + red[1][tid] + red[2][tid] + red[3][tid]) * rc[i];
}

// ---------- decode helper: 2 quant bytes -> float2 via fp16 bit trick ----------
__device__ __forceinline__ float2 d8x2(unsigned b0, unsigned b1) {
    unsigned pk = ((b0 + 64u) << 7) | ((b1 + 64u) << 23);
    return __half22float2(*reinterpret_cast<__half2*>(&pk));
}

// ---------- spin: wait until my 16 partials carry tag==k, sum them (R16) ----------
#define SPIN_SUM(vinp, kk, accv)                                               \
    {                                                                          \
        unsigned long long uv[16];                                             \
        _Pragma("unroll")                                                      \
        for (int p = 0; p < 16; p++) uv[p] = ALU((vinp) + p * N);              \
        unsigned miss = 0;                                                     \
        _Pragma("unroll")                                                      \
        for (int p = 0; p < 16; p++)                                           \
            if ((unsigned)(uv[p] >> 32) != (kk)) miss |= 1u << p;              \
        while (__builtin_expect(miss != 0, 0)) {                               \
            _Pragma("unroll")                                                  \
            for (int p = 0; p < 16; p++)                                       \
                if (miss & (1u << p)) {                                        \
                    unsigned long long t = ALU((vinp) + p * N);                \
                    if ((unsigned)(t >> 32) == (kk)) { uv[p] = t; miss &= ~(1u << p); } \
                }                                                              \
        }                                                                      \
        _Pragma("unroll")                                                      \
        for (int p = 0; p < 16; p++) accv += __uint_as_float((unsigned)uv[p]); \
    }

// ================== fp8 scan (mode 3) — R16 schedule (measured best, 9.9 ms) ==================
__global__ __launch_bounds__(256, 2) void scan8_kernel(const unsigned char* __restrict__ Q8,
                                                       const float* __restrict__ rc,
                                                       const float* __restrict__ OW,
                                                       const unsigned char* __restrict__ midx,
                                                       unsigned long long* __restrict__ vt,
                                                       float* __restrict__ out,
                                                       int S, int OPS) {
    const int tid = threadIdx.x;
    const int jb = blockIdx.x & 31;
    const int ic = blockIdx.x >> 5;      // 0..15
    const int i0 = ic * RPB;
    const int j0 = jb * CPB;

    __shared__ unsigned char mt8[2][RPB][CPB];   // 2 x 32 KiB fp8 tile
    __shared__ float v[RPB];
    __shared__ float vc[RPB];
    __shared__ float colacc[CPB];

    const int cg = tid & 15;
    const int rg = tid >> 4;

    const int w4 = tid >> 6;
    const int ln = tid & 63;
    const size_t goff8 = (size_t)(i0 + (ln >> 3)) * N + j0 + (ln & 7) * 16;

#define STAGE8(Mb, dst)                                                         \
    _Pragma("unroll")                                                           \
    for (int t = 0; t < 8; t++) {                                               \
        const int row0 = w4 * 64 + t * 8;                                       \
        __builtin_amdgcn_global_load_lds(                                       \
            (const __attribute__((address_space(1))) unsigned int*)((Mb) + goff8 + (size_t)row0 * N), \
            (__attribute__((address_space(3))) unsigned int*)((dst) + (size_t)row0 * CPB),            \
            16, 0, 0);                                                          \
    }

    int mcur = (int)midx[0];
    int mnxt = (S > 1) ? (int)midx[1] : 0;
    float rc_cur = rc[(size_t)mcur * N + i0 + tid];
    float rc_nxt = (S > 1) ? rc[(size_t)mnxt * N + i0 + tid] : 0.0f;
    STAGE8(Q8 + (size_t)mcur * NN, &mt8[0][0][0]);

    for (int k = 0; k < S; k++) {
        const int m = mcur;
        const unsigned long long* vinp = vt + (size_t)(k % 3) * VTN + (i0 + tid);
        unsigned long long* voutp = vt + (size_t)((k + 1) % 3) * VTN + (size_t)ic * N + j0;
        const unsigned char* mtc = &mt8[k & 1][0][0];

        float accv = 0.0f;
        SPIN_SUM(vinp, (unsigned)k, accv);
        v[tid] = accv;
        vc[tid] = accv * rc_cur;
        if (tid < CPB) colacc[tid] = 0.0f;

        if (k + 1 < S) {
            STAGE8(Q8 + (size_t)mnxt * NN, &mt8[(k + 1) & 1][0][0]);
            asm volatile("s_waitcnt vmcnt(8) lgkmcnt(0)" ::: "memory");
        } else {
            asm volatile("s_waitcnt vmcnt(0) lgkmcnt(0)" ::: "memory");
        }
        __builtin_amdgcn_s_barrier();
        __builtin_amdgcn_sched_barrier(0);

        float a[8];
#pragma unroll
        for (int e = 0; e < 8; e++) a[e] = 0.0f;
#pragma unroll
        for (int r = 0; r < 16; r++) {
            uint2 w = *(const uint2*)(mtc + (size_t)(rg * 16 + r) * CPB + cg * 8);
            float vi = vc[rg * 16 + r];
            float2 f0 = d8x2(w.x & 0xFF, (w.x >> 8) & 0xFF);
            float2 f1 = d8x2((w.x >> 16) & 0xFF, w.x >> 24);
            float2 f2 = d8x2(w.y & 0xFF, (w.y >> 8) & 0xFF);
            float2 f3 = d8x2((w.y >> 16) & 0xFF, w.y >> 24);
            a[0] += vi * f0.x; a[1] += vi * f0.y;
            a[2] += vi * f1.x; a[3] += vi * f1.y;
            a[4] += vi * f2.x; a[5] += vi * f2.y;
            a[6] += vi * f3.x; a[7] += vi * f3.y;
        }
#pragma unroll
        for (int e = 0; e < 8; e++) atomicAdd(&colacc[cg * 8 + e], a[e]);

        if (jb < OPS) {
            int slot;
            if (OPS == 4) slot = (jb == 0) ? (m >> 3) : (jb == 1) ? 2 + (m >> 2)
                               : (jb == 2) ? 6 + (m >> 1) : 14 + m;
            else if (OPS == 2) slot = (jb == 0) ? (m >> 1) : 2 + m;
            else slot = m;
            const float* pr = OW + (size_t)slot * SLOT;
            int r = tid >> 2, c = tid & 3;
            float p = v[r]       * pr[(size_t)(i0 + r) * 4 + c]
                    + v[r + 64]  * pr[(size_t)(i0 + r + 64) * 4 + c]
                    + v[r + 128] * pr[(size_t)(i0 + r + 128) * 4 + c]
                    + v[r + 192] * pr[(size_t)(i0 + r + 192) * 4 + c];
            p += __shfl_down(p, 32); p += __shfl_down(p, 16);
            p += __shfl_down(p, 8);  p += __shfl_down(p, 4);
            if ((tid & 63) < 4) atomicAdd(&out[(k * OPS + jb) * 4 + (tid & 3)], p);
        }

        asm volatile("s_waitcnt lgkmcnt(0)" ::: "memory");
        __builtin_amdgcn_s_barrier();
        __builtin_amdgcn_sched_barrier(0);

        if (tid < CPB) {
            unsigned long long pk = ((unsigned long long)(unsigned)(k + 1) << 32)
                                  | (unsigned long long)__float_as_uint(colacc[tid]);
            ASU(&voutp[tid], pk);
        }
        mcur = mnxt; rc_cur = rc_nxt;
        if (k + 2 < S) {
            mnxt = (int)midx[k + 2];
            rc_nxt = rc[(size_t)mnxt * N + i0 + tid];
        }
    }
#undef STAGE8
}

// ================== fp16 scan fallback (modes 0/1), tagged sync ==================
__global__ __launch_bounds__(256, 2) void scan16_kernel(const unsigned short* __restrict__ Mbase,
                                                        const float* __restrict__ rc,
                                                        const float* __restrict__ OW,
                                                        const unsigned char* __restrict__ midx,
                                                        unsigned long long* __restrict__ vt,
                                                        float* __restrict__ out,
                                                        int S, int OPS) {
    const int tid = threadIdx.x;
    const int jb = blockIdx.x & 31;
    const int ic = blockIdx.x >> 5;
    const int i0 = ic * RPB;
    const int j0 = jb * CPB;

    __shared__ unsigned short mt[RPB][CPB];
    __shared__ float v[RPB];
    __shared__ float vc[RPB];
    __shared__ float colacc[CPB];

    const int cg = tid & 15;
    const int rg = tid >> 4;

    const int w4 = tid >> 6;
    const int ln = tid & 63;
    const size_t goff = (size_t)(i0 + (ln >> 4)) * N + j0 + (ln & 15) * 8;

    int mcur = (int)midx[0];
    int mnxt = (S > 1) ? (int)midx[1] : 0;
    float rc_cur = rc[(size_t)mcur * N + i0 + tid];
    float rc_nxt = (S > 1) ? rc[(size_t)mnxt * N + i0 + tid] : 0.0f;
    {
        const unsigned short* Mb = Mbase + (size_t)mcur * NN;
#pragma unroll
        for (int t = 0; t < 16; t++) {
            const int row0 = w4 * 64 + t * 4;
            __builtin_amdgcn_global_load_lds(
                (const __attribute__((address_space(1))) unsigned int*)(Mb + goff + (size_t)row0 * N),
                (__attribute__((address_space(3))) unsigned int*)(&mt[row0][0]),
                16, 0, 0);
        }
    }

    for (int k = 0; k < S; k++) {
        const int m = mcur;
        const unsigned long long* vinp = vt + (size_t)(k % 3) * VTN + (i0 + tid);
        unsigned long long* voutp = vt + (size_t)((k + 1) % 3) * VTN + (size_t)ic * N + j0;

        float accv = 0.0f;
        SPIN_SUM(vinp, (unsigned)k, accv);
        v[tid] = accv;
        vc[tid] = accv * rc_cur;
        if (tid < CPB) colacc[tid] = 0.0f;
        __syncthreads();

        float a[8];
#pragma unroll
        for (int e = 0; e < 8; e++) a[e] = 0.0f;
#pragma unroll
        for (int r = 0; r < 16; r++) {
            uint4 w = *(const uint4*)&mt[rg * 16 + r][cg * 8];
            float vi = vc[rg * 16 + r];
            float2 f0 = __half22float2(*(__half2*)&w.x);
            float2 f1 = __half22float2(*(__half2*)&w.y);
            float2 f2 = __half22float2(*(__half2*)&w.z);
            float2 f3 = __half22float2(*(__half2*)&w.w);
            a[0] += vi * f0.x; a[1] += vi * f0.y;
            a[2] += vi * f1.x; a[3] += vi * f1.y;
            a[4] += vi * f2.x; a[5] += vi * f2.y;
            a[6] += vi * f3.x; a[7] += vi * f3.y;
        }
#pragma unroll
        for (int e = 0; e < 8; e++) atomicAdd(&colacc[cg * 8 + e], a[e]);

        if (jb < OPS) {
            int slot;
            if (OPS == 4) slot = (jb == 0) ? (m >> 3) : (jb == 1) ? 2 + (m >> 2)
                               : (jb == 2) ? 6 + (m >> 1) : 14 + m;
            else if (OPS == 2) slot = (jb == 0) ? (m >> 1) : 2 + m;
            else slot = m;
            const float* pr = OW + (size_t)slot * SLOT;
            int r = tid >> 2, c = tid & 3;
            float p = v[r]       * pr[(size_t)(i0 + r) * 4 + c]
                    + v[r + 64]  * pr[(size_t)(i0 + r + 64) * 4 + c]
                    + v[r + 128] * pr[(size_t)(i0 + r + 128) * 4 + c]
                    + v[r + 192] * pr[(size_t)(i0 + r + 192) * 4 + c];
            p += __shfl_down(p, 32); p += __shfl_down(p, 16);
            p += __shfl_down(p, 8);  p += __shfl_down(p, 4);
            if ((tid & 63) < 4) atomicAdd(&out[(k * OPS + jb) * 4 + (tid & 3)], p);
        }
        __syncthreads();

        if (tid < CPB) {
            unsigned long long pk = ((unsigned long long)(unsigned)(k + 1) << 32)
                                  | (unsigned long long)__float_as_uint(colacc[tid]);
            ASU(&voutp[tid], pk);
        }
        if (k + 1 < S) {
            const unsigned short* Mb = Mbase + (size_t)mnxt * NN;
#pragma unroll
            for (int t = 0; t < 16; t++) {
                const int row0 = w4 * 64 + t * 4;
                __builtin_amdgcn_global_load_lds(
                    (const __attribute__((address_space(1))) unsigned int*)(Mb + goff + (size_t)row0 * N),
                    (__attribute__((address_space(3))) unsigned int*)(&mt[row0][0]),
                    16, 0, 0);
            }
        }
        mcur = mnxt; rc_cur = rc_nxt;
        if (k + 2 < S) {
            mnxt = (int)midx[k + 2];
            rc_nxt = rc[(size_t)mnxt * N + i0 + tid];
        }
    }
}

extern "C" void kernel_launch(void* const* d_in, const int* in_sizes, int n_in,
                              void* d_out, int out_size, void* d_ws, size_t ws_size,
                              hipStream_t stream) {
    const float* sd  = (const float*)d_in[0];   // [4096]
    const int*   seq = (const int*)d_in[1];     // [4096]
    const float* T   = (const float*)d_in[2];   // [4096,2,4096]
    const float* O   = (const float*)d_in[3];   // [4096,2,4]
    float* out = (float*)d_out;                 // [4096,4]

    const size_t TM_SZ = 2 * NN * 2;            // 64 MiB
    const size_t P_SZ  = 4 * NN * 2;            // 128 MiB
    const size_t Q8_SZ = 16 * NN;               // 256 MiB fp8 matrices
    const size_t TB_SZ = NN * 2;                // 32 MiB transpose slice
    const size_t AUX_SZ = 0x400000;             // 4 MiB aux block

    // mode 3: Tm + P + Q8 + TB + aux = 484 MiB (ws measured in [452,644))
    int mode = (ws_size >= TM_SZ + P_SZ + Q8_SZ + TB_SZ + AUX_SZ) ? 3
             : (ws_size >= TM_SZ + P_SZ + TB_SZ + AUX_SZ) ? 1 : 0;

    char* ws = (char*)d_ws;
    unsigned short* Tm = (unsigned short*)ws;
    unsigned short* P  = (unsigned short*)(ws + TM_SZ);
    unsigned char*  Q8 = (unsigned char*)(ws + TM_SZ + P_SZ);
    unsigned short* TB = (unsigned short*)(ws + (mode == 3 ? TM_SZ + P_SZ + Q8_SZ
                                                           : TM_SZ + P_SZ));
    char* aux = (char*)TB + TB_SZ;
    if (mode == 0) aux = ws + TM_SZ;
    float* rowc   = (float*)(aux);               // 32 KB
    float* rowc2  = (float*)(aux + 0x8000);      // 64 KB
    float* rowc4  = (float*)(aux + 0x18000);     // 256 KB (rcacc -> rc in mode 3)
    float* OW     = (float*)(aux + 0x58000);     // 32 slots x 64 KB = 2 MB
    unsigned long long* vt = (unsigned long long*)(aux + 0x258000);  // 1.5 MiB tagged partials
    unsigned char* midx = (unsigned char*)(aux + 0x3D8000);

    hipLaunchKernelGGL(init_kernel, dim3(1536), dim3(256), 0, stream, sd, vt, rowc4, out);
    hipLaunchKernelGGL(build_desc_kernel, dim3(1), dim3(256), 0, stream, seq, midx,
                       mode == 3 ? 2 : mode);
    hipLaunchKernelGGL(softmax_T_kernel, dim3(2 * N), dim3(256), 0, stream, T, Tm, rowc);
    hipLaunchKernelGGL(softmax_O_kernel, dim3(32), dim3(256), 0, stream, O, OW);

    if (mode == 3) {
        // gemm0 in 2 sub-launches: P[a*2+b] = Tm_a x Tm_b (BT = TmT_b slice)
        for (int b = 0; b < 2; b++) {
            hipLaunchKernelGGL(transpose_kernel, dim3(4096), dim3(256), 0, stream,
                               Tm + (size_t)b * NN, TB);
            hipLaunchKernelGGL(HIP_KERNEL_NAME(gemm_kernel<0>), dim3(2 * 1024), dim3(256), 0, stream,
                               Tm, TB, (void*)P, rowc4, b, 2);
        }
        hipLaunchKernelGGL(rowsum_kernel, dim3(4 * N), dim3(256), 0, stream, P, rowc2);
        // proj before gemm1 (needs only Tm, P, rowc, rowc2)
        hipLaunchKernelGGL(proj_kernel, dim3(12 * N), dim3(256), 0, stream, Tm, P, rowc, rowc2, OW, 1);
        hipLaunchKernelGGL(proj_kernel, dim3(16 * N), dim3(256), 0, stream, Tm, P, rowc, rowc2, OW, 2);
        // gemm1 in 4 sub-launches: Q8[ab*4+cd] = P_ab x P_cd (BT = PT_cd slice)
        for (int cd = 0; cd < 4; cd++) {
            hipLaunchKernelGGL(transpose_kernel, dim3(4096), dim3(256), 0, stream,
                               P + (size_t)cd * NN, TB);
            hipLaunchKernelGGL(HIP_KERNEL_NAME(gemm_kernel<1>), dim3(4 * 1024), dim3(256), 0, stream,
                               P, TB, (void*)Q8, rowc4, cd, 4);
        }
        hipLaunchKernelGGL(rcinv_kernel, dim3(256), dim3(256), 0, stream, rowc4);
        hipLaunchKernelGGL(scan8_kernel, dim3(512), dim3(256), 0, stream,
                           Q8, rowc4, OW, midx, vt, out, L / 4, 4);
    } else if (mode == 1) {
        for (int b = 0; b < 2; b++) {
            hipLaunchKernelGGL(transpose_kernel, dim3(4096), dim3(256), 0, stream,
                               Tm + (size_t)b * NN, TB);
            hipLaunchKernelGGL(HIP_KERNEL_NAME(gemm_kernel<0>), dim3(2 * 1024), dim3(256), 0, stream,
                               Tm, TB, (void*)P, rowc4, b, 2);
        }
        hipLaunchKernelGGL(rowsum_kernel, dim3(4 * N), dim3(256), 0, stream, P, rowc2);
        hipLaunchKernelGGL(proj_kernel, dim3(4 * N), dim3(256), 0, stream, Tm, P, rowc, rowc2, OW, 1);
        hipLaunchKernelGGL(scan16_kernel, dim3(512), dim3(256), 0, stream,
                           P, rowc2, OW, midx, vt, out, L / 2, 2);
    } else {
        hipLaunchKernelGGL(scan16_kernel, dim3(512), dim3(256), 0, stream,
                           Tm, rowc, OW, midx, vt, out, L, 1);
    }
}

// Round 15
// 14293.768 us; speedup vs baseline: 1.4084x; 1.0145x over previous
//
#include <hip/hip_runtime.h>
#include <hip/hip_fp16.h>

#define N 4096
#define L 4096
#define NPART 16   // i-chunks (rows 256 each)
#define NJB 32     // j-blocks (cols 128 each)
#define CPB 128    // cols per block
#define RPB 256    // rows per block

#define NN ((size_t)N * (size_t)N)
#define SLOT ((size_t)N * 4)
#define VTN ((size_t)NPART * N)   // tagged-partial slots per buffer

#define ASU(p, v) __hip_atomic_store((p), (v), __ATOMIC_RELAXED, __HIP_MEMORY_SCOPE_AGENT)
#define ALU(p)    __hip_atomic_load((p), __ATOMIC_RELAXED, __HIP_MEMORY_SCOPE_AGENT)

typedef _Float16 f16x8 __attribute__((ext_vector_type(8)));
typedef float f32x4 __attribute__((ext_vector_type(4)));

// ---------- init: zero d_out, seed tagged triple buffer ----------
__global__ __launch_bounds__(256) void init_kernel(const float* __restrict__ sd,
                                                   unsigned long long* __restrict__ vt,
                                                   float* __restrict__ out) {
    int g = blockIdx.x * 256 + threadIdx.x;          // grid 1536 -> 393216 threads
    if (g < L * 4) out[g] = 0.0f;
    if (g < (int)(3 * VTN)) {
        float val = (g < N) ? sd[g] : 0.0f;          // buf0 partial0 = sd, tag 0
        ASU(&vt[g], (unsigned long long)__float_as_uint(val));
    }
}

// ---------- descriptor build ----------
__global__ __launch_bounds__(256) void build_desc_kernel(const int* __restrict__ seq32,
                                                         unsigned char* __restrict__ midx,
                                                         int mode) {
    __shared__ int any_odd;
    if (threadIdx.x == 0) any_odd = 0;
    __syncthreads();
    int acc = 0;
    for (int i = threadIdx.x; i < L / 2; i += 256) acc |= seq32[2 * i + 1];
    if (acc) any_odd = 1;
    __syncthreads();
    const int is64 = (any_odd == 0);
#define SYM(t) ((is64 ? seq32[2 * (t)] : seq32[(t)]) & 1)
    if (mode == 2) {
        for (int k = threadIdx.x; k < L / 4; k += 256)
            midx[k] = (unsigned char)(SYM(4 * k) * 8 + SYM(4 * k + 1) * 4 +
                                      SYM(4 * k + 2) * 2 + SYM(4 * k + 3));
    } else if (mode == 1) {
        for (int k = threadIdx.x; k < L / 2; k += 256)
            midx[k] = (unsigned char)(SYM(2 * k) * 2 + SYM(2 * k + 1));
    } else {
        for (int t = threadIdx.x; t < L; t += 256)
            midx[t] = (unsigned char)SYM(t);
    }
#undef SYM
}

// ---------- softmax over T rows -> fp16 Tm + row-mass correction ----------
__global__ __launch_bounds__(256) void softmax_T_kernel(const float* __restrict__ T,
                                                        unsigned short* __restrict__ Tm,
                                                        float* __restrict__ rowc) {
    int row = blockIdx.x;              // 0..8191 == i*2 + s
    int i = row >> 1, s = row & 1;
    const float* src = T + (size_t)row * N;
    unsigned short* dst = Tm + ((size_t)s << 24) + ((size_t)i << 12);
    int tid = threadIdx.x;

    float vals[16];
    float mx = -1e30f;
#pragma unroll
    for (int k = 0; k < 16; k++) {
        vals[k] = src[tid + (k << 8)];
        mx = fmaxf(mx, vals[k]);
    }
#pragma unroll
    for (int o = 32; o > 0; o >>= 1) mx = fmaxf(mx, __shfl_xor(mx, o));
    __shared__ float red[4];
    int wid = tid >> 6;
    if ((tid & 63) == 0) red[wid] = mx;
    __syncthreads();
    mx = fmaxf(fmaxf(red[0], red[1]), fmaxf(red[2], red[3]));
    __syncthreads();

    float sum = 0.0f;
#pragma unroll
    for (int k = 0; k < 16; k++) {
        vals[k] = __expf(vals[k] - mx);
        sum += vals[k];
    }
#pragma unroll
    for (int o = 32; o > 0; o >>= 1) sum += __shfl_xor(sum, o);
    if ((tid & 63) == 0) red[wid] = sum;
    __syncthreads();
    sum = red[0] + red[1] + red[2] + red[3];
    __syncthreads();
    float inv = 1.0f / sum;

    float qs = 0.0f;
#pragma unroll
    for (int k = 0; k < 16; k++) {
        __half h = __float2half_rn(vals[k] * inv);
        dst[tid + (k << 8)] = __half_as_ushort(h);
        qs += __half2float(h);
    }
#pragma unroll
    for (int o = 32; o > 0; o >>= 1) qs += __shfl_xor(qs, o);
    if ((tid & 63) == 0) red[wid] = qs;
    __syncthreads();
    if (tid == 0) {
        float q = red[0] + red[1] + red[2] + red[3];
        rowc[(size_t)s * N + i] = 1.0f / q;
    }
}

// ---------- softmax over O rows ----------
__global__ __launch_bounds__(256) void softmax_O_kernel(const float* __restrict__ O,
                                                        float* __restrict__ OW) {
    int r = blockIdx.x * 256 + threadIdx.x;
    if (r < 2 * N) {
        float4 x = *(const float4*)(O + (size_t)r * 4);
        float mx = fmaxf(fmaxf(x.x, x.y), fmaxf(x.z, x.w));
        float e0 = __expf(x.x - mx), e1 = __expf(x.y - mx);
        float e2 = __expf(x.z - mx), e3 = __expf(x.w - mx);
        float inv = 1.0f / (e0 + e1 + e2 + e3);
        int i = r >> 1, s = r & 1;
        *(float4*)(OW + (size_t)s * SLOT + (size_t)i * 4) =
            make_float4(e0 * inv, e1 * inv, e2 * inv, e3 * inv);
    }
}

// ---------- fp16 single-matrix transpose: 64x64 LDS tiles, grid 4096 ----------
__global__ __launch_bounds__(256) void transpose_kernel(const unsigned short* __restrict__ S0,
                                                        unsigned short* __restrict__ D0) {
    int b = blockIdx.x;                // 0..4095
    int ti = b >> 6, tj = b & 63;
    const unsigned short* S = S0 + (size_t)(ti * 64) * N + tj * 64;
    unsigned short* D = D0 + (size_t)(tj * 64) * N + ti * 64;

    __shared__ unsigned short tile[64][72];

    int tid = threadIdx.x;
    int r = tid >> 2, c0 = (tid & 3) * 16;
    *(uint4*)&tile[r][c0]     = *(const uint4*)(S + (size_t)r * N + c0);
    *(uint4*)&tile[r][c0 + 8] = *(const uint4*)(S + (size_t)r * N + c0 + 8);
    __syncthreads();

    int j = tid >> 2, i0 = (tid & 3) * 16;
    unsigned short g[16];
#pragma unroll
    for (int s = 0; s < 16; s++) g[s] = tile[i0 + s][j];
    *(uint4*)(D + (size_t)j * N + i0)     = *(const uint4*)&g[0];
    *(uint4*)(D + (size_t)j * N + i0 + 8) = *(const uint4*)&g[8];
}

// ---------- MFMA GEMM v3 (HW-verified): C = A[p] x BT^T ----------
// Both operands staged via global_load_lds, XOR-granule swizzle both sides.
// R21: Q8OUT=1 epilogue is PURE quantize+store — the decoded-rowsum global
// atomics (~1M contended 32-way adds across gemm1) moved to rowsum8_kernel.
template <int Q8OUT>
__global__ __launch_bounds__(256) void gemm_kernel(const unsigned short* __restrict__ Abase,
                                                   const unsigned short* __restrict__ BT,
                                                   void* __restrict__ Cbase,
                                                   int cidx_base, int cidx_stride) {
    const int nwg = gridDim.x;
    int bid0 = blockIdx.x;
    int bid = (bid0 & 7) * (nwg >> 3) + (bid0 >> 3);   // XCD-contiguous remap
    int pair = bid >> 10;
    int tile = bid & 1023;
    int i0 = (tile >> 5) << 7;
    int j0 = (tile & 31) << 7;
    const unsigned short* A = Abase + (size_t)pair * NN;
    const int cidx = cidx_base + pair * cidx_stride;

    __shared__ _Float16 Asd[128 * 64];        // 16 KB linear
    __shared__ _Float16 Bsd[128 * 64];        // 16 KB linear

    const int tid = threadIdx.x;
    const int w = tid >> 6, ln = tid & 63;
    const int wrow = (w >> 1) << 6, wcol = (w & 1) << 6;
    const int q = ln >> 4, l15 = ln & 15;

    const int gA = (ln & 7) ^ (ln >> 3);      // swizzled source granule

    f32x4 acc[4][4] = {};

    for (int k0 = 0; k0 < N; k0 += 64) {
#pragma unroll
        for (int t = 0; t < 4; t++) {
            const int rbase = w * 32 + t * 8;
            const int r = rbase + (ln >> 3);
            __builtin_amdgcn_global_load_lds(
                (const __attribute__((address_space(1))) unsigned int*)
                    (A + (size_t)(i0 + r) * N + k0 + gA * 8),
                (__attribute__((address_space(3))) unsigned int*)(Asd + rbase * 64),
                16, 0, 0);
        }
#pragma unroll
        for (int t = 0; t < 4; t++) {
            const int rbase = w * 32 + t * 8;
            const int r = rbase + (ln >> 3);
            __builtin_amdgcn_global_load_lds(
                (const __attribute__((address_space(1))) unsigned int*)
                    (BT + (size_t)(j0 + r) * N + k0 + gA * 8),
                (__attribute__((address_space(3))) unsigned int*)(Bsd + rbase * 64),
                16, 0, 0);
        }
        __syncthreads();   // drains gl_lds

#pragma unroll
        for (int kk = 0; kk < 2; kk++) {
            f16x8 af[4], bf[4];
#pragma unroll
            for (int ti = 0; ti < 4; ti++) {
                const int R = wrow + ti * 16 + l15;
                const int G = (kk * 4 + q) ^ (l15 & 7);
                af[ti] = *(const f16x8*)(Asd + R * 64 + G * 8);
            }
#pragma unroll
            for (int tj = 0; tj < 4; tj++) {
                const int R = wcol + tj * 16 + l15;
                const int G = (kk * 4 + q) ^ (l15 & 7);
                bf[tj] = *(const f16x8*)(Bsd + R * 64 + G * 8);
            }
#pragma unroll
            for (int ti = 0; ti < 4; ti++)
#pragma unroll
                for (int tj = 0; tj < 4; tj++)
                    acc[ti][tj] = __builtin_amdgcn_mfma_f32_16x16x32_f16(
                        af[ti], bf[tj], acc[ti][tj], 0, 0, 0);
        }
        __syncthreads();
    }

    if (Q8OUT == 0) {
        unsigned short* Pm = (unsigned short*)Cbase + (size_t)cidx * NN;
#pragma unroll
        for (int ti = 0; ti < 4; ti++)
#pragma unroll
            for (int tj = 0; tj < 4; tj++)
#pragma unroll
                for (int reg = 0; reg < 4; reg++) {
                    int row = i0 + wrow + ti * 16 + q * 4 + reg;
                    int col = j0 + wcol + tj * 16 + l15;
                    Pm[(size_t)row * N + col] =
                        __half_as_ushort(__float2half_rn(acc[ti][tj][reg]));
                }
    } else {
        unsigned char* Pm8 = (unsigned char*)Cbase + (size_t)cidx * NN;
#pragma unroll
        for (int ti = 0; ti < 4; ti++)
#pragma unroll
            for (int tj = 0; tj < 4; tj++)
#pragma unroll
                for (int reg = 0; reg < 4; reg++) {
                    int row = i0 + wrow + ti * 16 + q * 4 + reg;
                    float f = acc[ti][tj][reg] * 16384.0f;
                    unsigned hb = __half_as_ushort(__float2half_rn(f));
                    unsigned r = hb + 0x3Fu + ((hb >> 7) & 1u);   // rn-even into bit7
                    int qv = (int)(r >> 7) - 64;
                    qv = qv < 8 ? 8 : (qv > 0x7E ? 0x7E : qv);
                    Pm8[(size_t)row * N + j0 + wcol + tj * 16 + l15] = (unsigned char)qv;
                }
    }
}

// ---------- decode helper: 2 quant bytes -> float2 via fp16 bit trick ----------
__device__ __forceinline__ float2 d8x2(unsigned b0, unsigned b1) {
    unsigned pk = ((b0 + 64u) << 7) | ((b1 + 64u) << 23);
    return __half22float2(*reinterpret_cast<__half2*>(&pk));
}

// ---------- rc from quantized rows: rc[row] = 1 / sum(decode(Q8[row])) ----------
// One block per row (grid 16*N). Reads 256 MiB total, L3-warm.
__global__ __launch_bounds__(256) void rowsum8_kernel(const unsigned char* __restrict__ Q8,
                                                      float* __restrict__ rc) {
    size_t row = blockIdx.x;
    const unsigned char* src = Q8 + row * (size_t)N;
    int tid = threadIdx.x;
    uint4 wv = *(const uint4*)(src + tid * 16);
    unsigned uu[4] = {wv.x, wv.y, wv.z, wv.w};
    float s = 0.0f;
#pragma unroll
    for (int i = 0; i < 4; i++) {
        float2 f0 = d8x2(uu[i] & 0xFF, (uu[i] >> 8) & 0xFF);
        float2 f1 = d8x2((uu[i] >> 16) & 0xFF, uu[i] >> 24);
        s += f0.x + f0.y + f1.x + f1.y;
    }
#pragma unroll
    for (int o = 32; o > 0; o >>= 1) s += __shfl_xor(s, o);
    __shared__ float red[4];
    if ((tid & 63) == 0) red[tid >> 6] = s;
    __syncthreads();
    if (tid == 0) rc[row] = 1.0f / (red[0] + red[1] + red[2] + red[3]);
}

// ---------- row sums of fp16 matrices -> rc = 1/sum ----------
__global__ __launch_bounds__(256) void rowsum_kernel(const unsigned short* __restrict__ P,
                                                     float* __restrict__ rc) {
    int b = blockIdx.x;
    const unsigned short* row = P + (size_t)b * N;
    int tid = threadIdx.x;
    const uint4* rp = (const uint4*)row + tid * 2;
    uint4 w0 = rp[0], w1 = rp[1];
    const __half* h0 = (const __half*)&w0;
    const __half* h1 = (const __half*)&w1;
    float s = 0.0f;
#pragma unroll
    for (int j = 0; j < 8; j++) s += __half2float(h0[j]) + __half2float(h1[j]);
#pragma unroll
    for (int o = 32; o > 0; o >>= 1) s += __shfl_xor(s, o);
    __shared__ float red[4];
    if ((tid & 63) == 0) red[tid >> 6] = s;
    __syncthreads();
    if (tid == 0) rc[b] = 1.0f / (red[0] + red[1] + red[2] + red[3]);
}

// ---------- generic N x 4 projection (setup for OW slots) ----------
__global__ __launch_bounds__(256) void proj_kernel(const unsigned short* __restrict__ Tm,
                                                   const unsigned short* __restrict__ P,
                                                   const float* __restrict__ rowc,
                                                   const float* __restrict__ rowc2,
                                                   float* __restrict__ OW, int phase) {
    int bid = blockIdx.x;
    int s = bid >> 12, i = bid & 4095;
    const unsigned short* M; const float* rc; const float* Q; float* dst;
    if (phase == 1) {
        if (s < 4) { M = Tm + (size_t)(s >> 1) * NN; rc = rowc + (size_t)(s >> 1) * N;
                     Q = OW + (size_t)(s & 1) * SLOT; dst = OW + (size_t)(2 + s) * SLOT; }
        else { int q = s - 4; M = P + (size_t)(q >> 1) * NN; rc = rowc2 + (size_t)(q >> 1) * N;
               Q = OW + (size_t)(q & 1) * SLOT; dst = OW + (size_t)(6 + q) * SLOT; }
    } else {
        int q = s; M = P + (size_t)(q >> 2) * NN; rc = rowc2 + (size_t)(q >> 2) * N;
        Q = OW + (size_t)(2 + (q & 3)) * SLOT; dst = OW + (size_t)(14 + q) * SLOT;
    }
    const unsigned short* row = M + (size_t)i * N;
    int tid = threadIdx.x;
    const uint4* rp = (const uint4*)row + tid * 2;
    uint4 w0 = rp[0], w1 = rp[1];
    const __half* h0 = (const __half*)&w0;
    const __half* h1 = (const __half*)&w1;
    int j0 = tid * 16;
    float ac[4] = {};
#pragma unroll
    for (int j = 0; j < 8; j++) {
        float tv = __half2float(h0[j]);
        float4 o = *(const float4*)(Q + (size_t)(j0 + j) * 4);
        ac[0] += tv * o.x; ac[1] += tv * o.y; ac[2] += tv * o.z; ac[3] += tv * o.w;
        float tv1 = __half2float(h1[j]);
        float4 o1 = *(const float4*)(Q + (size_t)(j0 + 8 + j) * 4);
        ac[0] += tv1 * o1.x; ac[1] += tv1 * o1.y; ac[2] += tv1 * o1.z; ac[3] += tv1 * o1.w;
    }
#pragma unroll
    for (int e = 0; e < 4; e++)
#pragma unroll
        for (int o = 32; o > 0; o >>= 1) ac[e] += __shfl_xor(ac[e], o);
    __shared__ float red[4][4];
    if ((tid & 63) == 0)
#pragma unroll
        for (int e = 0; e < 4; e++) red[tid >> 6][e] = ac[e];
    __syncthreads();
    if (tid < 4)
        dst[(size_t)i * 4 + tid] =
            (red[0][tid] + red[1][tid] + red[2][tid] + red[3][tid]) * rc[i];
}

// ---------- spin: wait until my 16 partials carry tag==k, sum them (R16) ----------
#define SPIN_SUM(vinp, kk, accv)                                               \
    {                                                                          \
        unsigned long long uv[16];                                             \
        _Pragma("unroll")                                                      \
        for (int p = 0; p < 16; p++) uv[p] = ALU((vinp) + p * N);              \
        unsigned miss = 0;                                                     \
        _Pragma("unroll")                                                      \
        for (int p = 0; p < 16; p++)                                           \
            if ((unsigned)(uv[p] >> 32) != (kk)) miss |= 1u << p;              \
        while (__builtin_expect(miss != 0, 0)) {                               \
            _Pragma("unroll")                                                  \
            for (int p = 0; p < 16; p++)                                       \
                if (miss & (1u << p)) {                                        \
                    unsigned long long t = ALU((vinp) + p * N);                \
                    if ((unsigned)(t >> 32) == (kk)) { uv[p] = t; miss &= ~(1u << p); } \
                }                                                              \
        }                                                                      \
        _Pragma("unroll")                                                      \
        for (int p = 0; p < 16; p++) accv += __uint_as_float((unsigned)uv[p]); \
    }

// ================== fp8 scan (mode 3) — R16 schedule (measured best, 9.9 ms) ==================
__global__ __launch_bounds__(256, 2) void scan8_kernel(const unsigned char* __restrict__ Q8,
                                                       const float* __restrict__ rc,
                                                       const float* __restrict__ OW,
                                                       const unsigned char* __restrict__ midx,
                                                       unsigned long long* __restrict__ vt,
                                                       float* __restrict__ out,
                                                       int S, int OPS) {
    const int tid = threadIdx.x;
    const int jb = blockIdx.x & 31;
    const int ic = blockIdx.x >> 5;      // 0..15
    const int i0 = ic * RPB;
    const int j0 = jb * CPB;

    __shared__ unsigned char mt8[2][RPB][CPB];   // 2 x 32 KiB fp8 tile
    __shared__ float v[RPB];
    __shared__ float vc[RPB];
    __shared__ float colacc[CPB];

    const int cg = tid & 15;
    const int rg = tid >> 4;

    const int w4 = tid >> 6;
    const int ln = tid & 63;
    const size_t goff8 = (size_t)(i0 + (ln >> 3)) * N + j0 + (ln & 7) * 16;

#define STAGE8(Mb, dst)                                                         \
    _Pragma("unroll")                                                           \
    for (int t = 0; t < 8; t++) {                                               \
        const int row0 = w4 * 64 + t * 8;                                       \
        __builtin_amdgcn_global_load_lds(                                       \
            (const __attribute__((address_space(1))) unsigned int*)((Mb) + goff8 + (size_t)row0 * N), \
            (__attribute__((address_space(3))) unsigned int*)((dst) + (size_t)row0 * CPB),            \
            16, 0, 0);                                                          \
    }

    int mcur = (int)midx[0];
    int mnxt = (S > 1) ? (int)midx[1] : 0;
    float rc_cur = rc[(size_t)mcur * N + i0 + tid];
    float rc_nxt = (S > 1) ? rc[(size_t)mnxt * N + i0 + tid] : 0.0f;
    STAGE8(Q8 + (size_t)mcur * NN, &mt8[0][0][0]);

    for (int k = 0; k < S; k++) {
        const int m = mcur;
        const unsigned long long* vinp = vt + (size_t)(k % 3) * VTN + (i0 + tid);
        unsigned long long* voutp = vt + (size_t)((k + 1) % 3) * VTN + (size_t)ic * N + j0;
        const unsigned char* mtc = &mt8[k & 1][0][0];

        float accv = 0.0f;
        SPIN_SUM(vinp, (unsigned)k, accv);
        v[tid] = accv;
        vc[tid] = accv * rc_cur;
        if (tid < CPB) colacc[tid] = 0.0f;

        if (k + 1 < S) {
            STAGE8(Q8 + (size_t)mnxt * NN, &mt8[(k + 1) & 1][0][0]);
            asm volatile("s_waitcnt vmcnt(8) lgkmcnt(0)" ::: "memory");
        } else {
            asm volatile("s_waitcnt vmcnt(0) lgkmcnt(0)" ::: "memory");
        }
        __builtin_amdgcn_s_barrier();
        __builtin_amdgcn_sched_barrier(0);

        float a[8];
#pragma unroll
        for (int e = 0; e < 8; e++) a[e] = 0.0f;
#pragma unroll
        for (int r = 0; r < 16; r++) {
            uint2 w = *(const uint2*)(mtc + (size_t)(rg * 16 + r) * CPB + cg * 8);
            float vi = vc[rg * 16 + r];
            float2 f0 = d8x2(w.x & 0xFF, (w.x >> 8) & 0xFF);
            float2 f1 = d8x2((w.x >> 16) & 0xFF, w.x >> 24);
            float2 f2 = d8x2(w.y & 0xFF, (w.y >> 8) & 0xFF);
            float2 f3 = d8x2((w.y >> 16) & 0xFF, w.y >> 24);
            a[0] += vi * f0.x; a[1] += vi * f0.y;
            a[2] += vi * f1.x; a[3] += vi * f1.y;
            a[4] += vi * f2.x; a[5] += vi * f2.y;
            a[6] += vi * f3.x; a[7] += vi * f3.y;
        }
#pragma unroll
        for (int e = 0; e < 8; e++) atomicAdd(&colacc[cg * 8 + e], a[e]);

        if (jb < OPS) {
            int slot;
            if (OPS == 4) slot = (jb == 0) ? (m >> 3) : (jb == 1) ? 2 + (m >> 2)
                               : (jb == 2) ? 6 + (m >> 1) : 14 + m;
            else if (OPS == 2) slot = (jb == 0) ? (m >> 1) : 2 + m;
            else slot = m;
            const float* pr = OW + (size_t)slot * SLOT;
            int r = tid >> 2, c = tid & 3;
            float p = v[r]       * pr[(size_t)(i0 + r) * 4 + c]
                    + v[r + 64]  * pr[(size_t)(i0 + r + 64) * 4 + c]
                    + v[r + 128] * pr[(size_t)(i0 + r + 128) * 4 + c]
                    + v[r + 192] * pr[(size_t)(i0 + r + 192) * 4 + c];
            p += __shfl_down(p, 32); p += __shfl_down(p, 16);
            p += __shfl_down(p, 8);  p += __shfl_down(p, 4);
            if ((tid & 63) < 4) atomicAdd(&out[(k * OPS + jb) * 4 + (tid & 3)], p);
        }

        asm volatile("s_waitcnt lgkmcnt(0)" ::: "memory");
        __builtin_amdgcn_s_barrier();
        __builtin_amdgcn_sched_barrier(0);

        if (tid < CPB) {
            unsigned long long pk = ((unsigned long long)(unsigned)(k + 1) << 32)
                                  | (unsigned long long)__float_as_uint(colacc[tid]);
            ASU(&voutp[tid], pk);
        }
        mcur = mnxt; rc_cur = rc_nxt;
        if (k + 2 < S) {
            mnxt = (int)midx[k + 2];
            rc_nxt = rc[(size_t)mnxt * N + i0 + tid];
        }
    }
#undef STAGE8
}

// ================== fp16 scan fallback (modes 0/1), tagged sync ==================
__global__ __launch_bounds__(256, 2) void scan16_kernel(const unsigned short* __restrict__ Mbase,
                                                        const float* __restrict__ rc,
                                                        const float* __restrict__ OW,
                                                        const unsigned char* __restrict__ midx,
                                                        unsigned long long* __restrict__ vt,
                                                        float* __restrict__ out,
                                                        int S, int OPS) {
    const int tid = threadIdx.x;
    const int jb = blockIdx.x & 31;
    const int ic = blockIdx.x >> 5;
    const int i0 = ic * RPB;
    const int j0 = jb * CPB;

    __shared__ unsigned short mt[RPB][CPB];
    __shared__ float v[RPB];
    __shared__ float vc[RPB];
    __shared__ float colacc[CPB];

    const int cg = tid & 15;
    const int rg = tid >> 4;

    const int w4 = tid >> 6;
    const int ln = tid & 63;
    const size_t goff = (size_t)(i0 + (ln >> 4)) * N + j0 + (ln & 15) * 8;

    int mcur = (int)midx[0];
    int mnxt = (S > 1) ? (int)midx[1] : 0;
    float rc_cur = rc[(size_t)mcur * N + i0 + tid];
    float rc_nxt = (S > 1) ? rc[(size_t)mnxt * N + i0 + tid] : 0.0f;
    {
        const unsigned short* Mb = Mbase + (size_t)mcur * NN;
#pragma unroll
        for (int t = 0; t < 16; t++) {
            const int row0 = w4 * 64 + t * 4;
            __builtin_amdgcn_global_load_lds(
                (const __attribute__((address_space(1))) unsigned int*)(Mb + goff + (size_t)row0 * N),
                (__attribute__((address_space(3))) unsigned int*)(&mt[row0][0]),
                16, 0, 0);
        }
    }

    for (int k = 0; k < S; k++) {
        const int m = mcur;
        const unsigned long long* vinp = vt + (size_t)(k % 3) * VTN + (i0 + tid);
        unsigned long long* voutp = vt + (size_t)((k + 1) % 3) * VTN + (size_t)ic * N + j0;

        float accv = 0.0f;
        SPIN_SUM(vinp, (unsigned)k, accv);
        v[tid] = accv;
        vc[tid] = accv * rc_cur;
        if (tid < CPB) colacc[tid] = 0.0f;
        __syncthreads();

        float a[8];
#pragma unroll
        for (int e = 0; e < 8; e++) a[e] = 0.0f;
#pragma unroll
        for (int r = 0; r < 16; r++) {
            uint4 w = *(const uint4*)&mt[rg * 16 + r][cg * 8];
            float vi = vc[rg * 16 + r];
            float2 f0 = __half22float2(*(__half2*)&w.x);
            float2 f1 = __half22float2(*(__half2*)&w.y);
            float2 f2 = __half22float2(*(__half2*)&w.z);
            float2 f3 = __half22float2(*(__half2*)&w.w);
            a[0] += vi * f0.x; a[1] += vi * f0.y;
            a[2] += vi * f1.x; a[3] += vi * f1.y;
            a[4] += vi * f2.x; a[5] += vi * f2.y;
            a[6] += vi * f3.x; a[7] += vi * f3.y;
        }
#pragma unroll
        for (int e = 0; e < 8; e++) atomicAdd(&colacc[cg * 8 + e], a[e]);

        if (jb < OPS) {
            int slot;
            if (OPS == 4) slot = (jb == 0) ? (m >> 3) : (jb == 1) ? 2 + (m >> 2)
                               : (jb == 2) ? 6 + (m >> 1) : 14 + m;
            else if (OPS == 2) slot = (jb == 0) ? (m >> 1) : 2 + m;
            else slot = m;
            const float* pr = OW + (size_t)slot * SLOT;
            int r = tid >> 2, c = tid & 3;
            float p = v[r]       * pr[(size_t)(i0 + r) * 4 + c]
                    + v[r + 64]  * pr[(size_t)(i0 + r + 64) * 4 + c]
                    + v[r + 128] * pr[(size_t)(i0 + r + 128) * 4 + c]
                    + v[r + 192] * pr[(size_t)(i0 + r + 192) * 4 + c];
            p += __shfl_down(p, 32); p += __shfl_down(p, 16);
            p += __shfl_down(p, 8);  p += __shfl_down(p, 4);
            if ((tid & 63) < 4) atomicAdd(&out[(k * OPS + jb) * 4 + (tid & 3)], p);
        }
        __syncthreads();

        if (tid < CPB) {
            unsigned long long pk = ((unsigned long long)(unsigned)(k + 1) << 32)
                                  | (unsigned long long)__float_as_uint(colacc[tid]);
            ASU(&voutp[tid], pk);
        }
        if (k + 1 < S) {
            const unsigned short* Mb = Mbase + (size_t)mnxt * NN;
#pragma unroll
            for (int t = 0; t < 16; t++) {
                const int row0 = w4 * 64 + t * 4;
                __builtin_amdgcn_global_load_lds(
                    (const __attribute__((address_space(1))) unsigned int*)(Mb + goff + (size_t)row0 * N),
                    (__attribute__((address_space(3))) unsigned int*)(&mt[row0][0]),
                    16, 0, 0);
            }
        }
        mcur = mnxt; rc_cur = rc_nxt;
        if (k + 2 < S) {
            mnxt = (int)midx[k + 2];
            rc_nxt = rc[(size_t)mnxt * N + i0 + tid];
        }
    }
}

extern "C" void kernel_launch(void* const* d_in, const int* in_sizes, int n_in,
                              void* d_out, int out_size, void* d_ws, size_t ws_size,
                              hipStream_t stream) {
    const float* sd  = (const float*)d_in[0];   // [4096]
    const int*   seq = (const int*)d_in[1];     // [4096]
    const float* T   = (const float*)d_in[2];   // [4096,2,4096]
    const float* O   = (const float*)d_in[3];   // [4096,2,4]
    float* out = (float*)d_out;                 // [4096,4]

    const size_t TM_SZ = 2 * NN * 2;            // 64 MiB
    const size_t P_SZ  = 4 * NN * 2;            // 128 MiB
    const size_t Q8_SZ = 16 * NN;               // 256 MiB fp8 matrices
    const size_t TB_SZ = NN * 2;                // 32 MiB transpose slice
    const size_t AUX_SZ = 0x400000;             // 4 MiB aux block

    // mode 3: Tm + P + Q8 + TB + aux = 484 MiB (ws measured in [452,644))
    int mode = (ws_size >= TM_SZ + P_SZ + Q8_SZ + TB_SZ + AUX_SZ) ? 3
             : (ws_size >= TM_SZ + P_SZ + TB_SZ + AUX_SZ) ? 1 : 0;

    char* ws = (char*)d_ws;
    unsigned short* Tm = (unsigned short*)ws;
    unsigned short* P  = (unsigned short*)(ws + TM_SZ);
    unsigned char*  Q8 = (unsigned char*)(ws + TM_SZ + P_SZ);
    unsigned short* TB = (unsigned short*)(ws + (mode == 3 ? TM_SZ + P_SZ + Q8_SZ
                                                           : TM_SZ + P_SZ));
    char* aux = (char*)TB + TB_SZ;
    if (mode == 0) aux = ws + TM_SZ;
    float* rowc   = (float*)(aux);               // 32 KB
    float* rowc2  = (float*)(aux + 0x8000);      // 64 KB
    float* rowc4  = (float*)(aux + 0x18000);     // 256 KB (rc for 16 matrices)
    float* OW     = (float*)(aux + 0x58000);     // 32 slots x 64 KB = 2 MB
    unsigned long long* vt = (unsigned long long*)(aux + 0x258000);  // 1.5 MiB tagged partials
    unsigned char* midx = (unsigned char*)(aux + 0x3D8000);

    hipLaunchKernelGGL(init_kernel, dim3(1536), dim3(256), 0, stream, sd, vt, out);
    hipLaunchKernelGGL(build_desc_kernel, dim3(1), dim3(256), 0, stream, seq, midx,
                       mode == 3 ? 2 : mode);
    hipLaunchKernelGGL(softmax_T_kernel, dim3(2 * N), dim3(256), 0, stream, T, Tm, rowc);
    hipLaunchKernelGGL(softmax_O_kernel, dim3(32), dim3(256), 0, stream, O, OW);

    if (mode == 3) {
        // gemm0 in 2 sub-launches: P[a*2+b] = Tm_a x Tm_b (BT = TmT_b slice)
        for (int b = 0; b < 2; b++) {
            hipLaunchKernelGGL(transpose_kernel, dim3(4096), dim3(256), 0, stream,
                               Tm + (size_t)b * NN, TB);
            hipLaunchKernelGGL(HIP_KERNEL_NAME(gemm_kernel<0>), dim3(2 * 1024), dim3(256), 0, stream,
                               Tm, TB, (void*)P, b, 2);
        }
        hipLaunchKernelGGL(rowsum_kernel, dim3(4 * N), dim3(256), 0, stream, P, rowc2);
        // proj before gemm1 (needs only Tm, P, rowc, rowc2)
        hipLaunchKernelGGL(proj_kernel, dim3(12 * N), dim3(256), 0, stream, Tm, P, rowc, rowc2, OW, 1);
        hipLaunchKernelGGL(proj_kernel, dim3(16 * N), dim3(256), 0, stream, Tm, P, rowc, rowc2, OW, 2);
        // gemm1 in 4 sub-launches: Q8[ab*4+cd] = P_ab x P_cd (BT = PT_cd slice)
        for (int cd = 0; cd < 4; cd++) {
            hipLaunchKernelGGL(transpose_kernel, dim3(4096), dim3(256), 0, stream,
                               P + (size_t)cd * NN, TB);
            hipLaunchKernelGGL(HIP_KERNEL_NAME(gemm_kernel<1>), dim3(4 * 1024), dim3(256), 0, stream,
                               P, TB, (void*)Q8, cd, 4);
        }
        // rc from quantized matrices (replaces in-gemm atomics + rcinv)
        hipLaunchKernelGGL(rowsum8_kernel, dim3(16 * N), dim3(256), 0, stream, Q8, rowc4);
        hipLaunchKernelGGL(scan8_kernel, dim3(512), dim3(256), 0, stream,
                           Q8, rowc4, OW, midx, vt, out, L / 4, 4);
    } else if (mode == 1) {
        for (int b = 0; b < 2; b++) {
            hipLaunchKernelGGL(transpose_kernel, dim3(4096), dim3(256), 0, stream,
                               Tm + (size_t)b * NN, TB);
            hipLaunchKernelGGL(HIP_KERNEL_NAME(gemm_kernel<0>), dim3(2 * 1024), dim3(256), 0, stream,
                               Tm, TB, (void*)P, b, 2);
        }
        hipLaunchKernelGGL(rowsum_kernel, dim3(4 * N), dim3(256), 0, stream, P, rowc2);
        hipLaunchKernelGGL(proj_kernel, dim3(4 * N), dim3(256), 0, stream, Tm, P, rowc, rowc2, OW, 1);
        hipLaunchKernelGGL(scan16_kernel, dim3(512), dim3(256), 0, stream,
                           P, rowc2, OW, midx, vt, out, L / 2, 2);
    } else {
        hipLaunchKernelGGL(scan16_kernel, dim3(512), dim3(256), 0, stream,
                           Tm, rowc, OW, midx, vt, out, L, 1);
    }
}